// Round 7
// baseline (175.634 us; speedup 1.0000x reference)
//
#include <hip/hip_runtime.h>
#include <hip/hip_bf16.h>

#define NEDGE 320000
#define NNODE 20000
#define MP    20096      // 157*128 padded rows
#define NRELS 8
#define NSEG  (NNODE*NRELS)   // 160000
#define FEAT  128
#define HID   256
#define EMB   128
#define NGRAPH 20
#define NPG   1000
#define NBASE 4

typedef __attribute__((ext_vector_type(4))) float f32x4;
typedef __attribute__((ext_vector_type(8))) __bf16 bf16x8;

static __device__ __forceinline__ float bf2f(unsigned short u){
  union { unsigned int i; float f; } v; v.i = ((unsigned int)u) << 16; return v.f;
}
static __device__ __forceinline__ unsigned short f2bf(float f){
  union { float f; unsigned int i; } v; v.f = f;
  unsigned int x = v.i;
  return (unsigned short)((x + 0x7fffu + ((x >> 16) & 1u)) >> 16);
}

__device__ __forceinline__ void load_lds16(const void* g, void* l){
  __builtin_amdgcn_global_load_lds((const __attribute__((address_space(1))) void*)g,
                                   (__attribute__((address_space(3))) void*)l, 16, 0, 0);
}

// ---------------- init ----------------
__global__ void k_zero(int* __restrict__ cnt, int* __restrict__ total,
                       float* __restrict__ zbias, unsigned short* __restrict__ BtV){
  int i = blockIdx.x*256 + threadIdx.x;
  if (i < NSEG) cnt[i] = 0;
  if (i < 128) zbias[i] = 0.f;
  if (i < 28*256) BtV[100*256 + i] = 0;   // rows 100..127 unused but fed to MFMA
  if (i == 0) *total = 0;
}

// ---------------- edge preprocessing ----------------
__global__ void k_hist(const int* __restrict__ ei, const int* __restrict__ et, int* __restrict__ cnt){
  int e = blockIdx.x*256 + threadIdx.x;
  if (e < NEDGE){
    int key = ei[NEDGE + e]*NRELS + et[e];
    atomicAdd(&cnt[key], 1);
  }
}

// Disjoint contiguous ranges per segment: wave prefix + one atomic per wave.
// Within a wave (64 consecutive keys) ranges are contiguous & key-ordered, so the
// 8 segments of any node n form ONE contiguous range.
__global__ void k_offsets(const int* __restrict__ cnt, int* __restrict__ offs,
                          int* __restrict__ cursor, int* __restrict__ total){
  int i = blockIdx.x*256 + threadIdx.x;
  int lane = threadIdx.x & 63;
  int c = (i < NSEG) ? cnt[i] : 0;
  int inc = c;
  #pragma unroll
  for (int d=1; d<64; d<<=1){
    int v = __shfl_up(inc, d);
    if (lane >= d) inc += v;
  }
  __shared__ int wbase[4];
  if (lane == 63) wbase[threadIdx.x>>6] = atomicAdd(total, inc);
  __syncthreads();
  if (i < NSEG){
    int base = wbase[threadIdx.x>>6] + inc - c;
    offs[i] = base;
    cursor[i] = base;
  }
}

// scatter sorted src + per-edge basis weights w_b = comp[r,b]/cnt(seg)
__global__ void k_scatter(const int* __restrict__ ei, const int* __restrict__ et,
                          const int* __restrict__ cnt, int* __restrict__ cursor,
                          const float* __restrict__ comp1, const float* __restrict__ comp2,
                          int* __restrict__ ssrc, float4* __restrict__ wts1, float4* __restrict__ wts2){
  int e = blockIdx.x*256 + threadIdx.x;
  if (e < NEDGE){
    int src = ei[e];
    int r = et[e];
    int key = ei[NEDGE + e]*NRELS + r;
    int pos = atomicAdd(&cursor[key], 1);
    float inv = 1.f / (float)cnt[key];
    ssrc[pos] = src;
    float4 w1, w2;
    w1.x = comp1[r*4+0]*inv; w1.y = comp1[r*4+1]*inv; w1.z = comp1[r*4+2]*inv; w1.w = comp1[r*4+3]*inv;
    w2.x = comp2[r*4+0]*inv; w2.y = comp2[r*4+1]*inv; w2.z = comp2[r*4+2]*inv; w2.w = comp2[r*4+3]*inv;
    wts1[pos] = w1;
    wts2[pos] = w2;
  }
}

// ---------------- layer1 basis aggregation ----------------
// half-wave (32 lanes x ushort4) per node, unroll 4 -> 8 gathers in flight per wave
// s1[n][b*128 + d] = sum_edges w1[b] * xb[src][d]
__global__ void k_agg1(const unsigned short* __restrict__ xb, const int* __restrict__ offs,
                       const int* __restrict__ cnt, const int* __restrict__ ssrc,
                       const float4* __restrict__ wts,
                       unsigned short* __restrict__ s1){
  int half = threadIdx.x >> 5, sl = threadIdx.x & 31;
  int n = blockIdx.x*8 + half;
  if (n >= NNODE) return;
  int o0 = offs[n*NRELS];
  int C  = offs[n*NRELS+7] + cnt[n*NRELS+7] - o0;
  const int* sp = ssrc + o0;
  const float4* wp = wts + o0;
  float u[NBASE][4] = {};
  int j = 0;
  for (; j+4 <= C; j += 4){
    int s0=sp[j], s1i=sp[j+1], s2i=sp[j+2], s3i=sp[j+3];
    float4 w0=wp[j], w1=wp[j+1], w2=wp[j+2], w3=wp[j+3];
    ushort4 v0 = *(const ushort4*)(xb + (size_t)s0*FEAT + sl*4);
    ushort4 v1 = *(const ushort4*)(xb + (size_t)s1i*FEAT + sl*4);
    ushort4 v2 = *(const ushort4*)(xb + (size_t)s2i*FEAT + sl*4);
    ushort4 v3 = *(const ushort4*)(xb + (size_t)s3i*FEAT + sl*4);
    float f0[4] = {bf2f(v0.x),bf2f(v0.y),bf2f(v0.z),bf2f(v0.w)};
    float f1[4] = {bf2f(v1.x),bf2f(v1.y),bf2f(v1.z),bf2f(v1.w)};
    float f2[4] = {bf2f(v2.x),bf2f(v2.y),bf2f(v2.z),bf2f(v2.w)};
    float f3[4] = {bf2f(v3.x),bf2f(v3.y),bf2f(v3.z),bf2f(v3.w)};
    #pragma unroll
    for (int b=0;b<NBASE;b++){
      float wb0=((const float*)&w0)[b], wb1=((const float*)&w1)[b];
      float wb2=((const float*)&w2)[b], wb3=((const float*)&w3)[b];
      #pragma unroll
      for (int k=0;k<4;k++)
        u[b][k] += wb0*f0[k] + wb1*f1[k] + wb2*f2[k] + wb3*f3[k];
    }
  }
  for (; j < C; ++j){
    int s = sp[j];
    float4 wv = wp[j];
    ushort4 v = *(const ushort4*)(xb + (size_t)s*FEAT + sl*4);
    float f[4] = {bf2f(v.x),bf2f(v.y),bf2f(v.z),bf2f(v.w)};
    #pragma unroll
    for (int b=0;b<NBASE;b++){
      float wb = ((const float*)&wv)[b];
      #pragma unroll
      for (int k=0;k<4;k++) u[b][k] += wb*f[k];
    }
  }
  #pragma unroll
  for (int b=0;b<NBASE;b++){
    ushort4 o4;
    o4.x = f2bf(u[b][0]); o4.y = f2bf(u[b][1]); o4.z = f2bf(u[b][2]); o4.w = f2bf(u[b][3]);
    *(ushort4*)(s1 + (size_t)n*(NBASE*FEAT) + b*FEAT + sl*4) = o4;
  }
}

// ---------------- fused weight prep: cvt node_x -> bf16  +  B1t gen ----------------
__global__ void k_prep1(const float* __restrict__ xin, unsigned short* __restrict__ xb,
                        const float* __restrict__ basis, const float* __restrict__ root,
                        unsigned short* __restrict__ Bt){
  int blk = blockIdx.x;
  if (blk < 10000){
    int i = blk*256 + threadIdx.x;
    if (i < NNODE*FEAT) xb[i] = f2bf(xin[i]);
  } else {
    int idx = (blk-10000)*256 + threadIdx.x;
    if (idx >= 256*640) return;
    int o = idx / 640, k = idx % 640;
    float v = (k < 512) ? basis[(size_t)k*256 + o] : root[(size_t)(k-512)*256 + o];
    Bt[(size_t)o*640 + k] = f2bf(v);
  }
}

// ---------------- fused head prep: me[g] then BtV rows for graph g ----------------
// BtV [128 c][256 k] bf16: c=4g+b -> dot(basis2[b*256+k], me[g]); c=80+g -> dot(root2[k], me[g])
__global__ void k_prepV(const float* __restrict__ x, const float* __restrict__ mw,
                        const float* __restrict__ mb,
                        const float* __restrict__ basis2, const float* __restrict__ root2,
                        unsigned short* __restrict__ BtV){
  __shared__ float me_s[EMB];
  int g = blockIdx.x, t = threadIdx.x;
  if (t < EMB){
    float s = mb[t];
    for (int i=0;i<HID;i++) s += x[g*HID + i] * mw[i*EMB + t];
    me_s[t] = s;
  }
  __syncthreads();
  for (int tcol = t; tcol < 1280; tcol += 256){
    const float* row; int c, k;
    if (tcol < 1024){ int b = tcol>>8; k = tcol&255; row = basis2 + (size_t)(b*256+k)*EMB; c = 4*g+b; }
    else            { k = tcol-1024;  row = root2 + (size_t)k*EMB; c = 80+g; }
    float s = 0.f;
    #pragma unroll 4
    for (int i=0;i<EMB;i++) s += row[i]*me_s[i];
    BtV[(size_t)c*256 + k] = f2bf(s);
  }
}

// ---------------- GEMM: C[M x 128tile] = [A0|A1] @ Bt^T ----------------
template<int BM, bool RELU>
__global__ __launch_bounds__(256, 2)
void k_gemm(const unsigned short* __restrict__ A0, int ldA0,
            const unsigned short* __restrict__ A1, int ldA1, int K0, int K,
            const unsigned short* __restrict__ Bt,
            const float* __restrict__ bias,
            unsigned short* __restrict__ Cb, float* __restrict__ Cf, int ldC)
{
  constexpr int BK = 64;
  constexpr int FM = BM/32;
  constexpr int TA = BM*8/256;
  __shared__ __align__(16) unsigned short As[BM*BK];
  __shared__ __align__(16) unsigned short Bs[128*BK];

  const int tid  = threadIdx.x;
  const int w    = tid >> 6, lane = tid & 63;
  const int wr   = w >> 1,  wc   = w & 1;
  const int m0   = blockIdx.x * BM;
  const int n0   = blockIdx.y * 128;

  const f32x4 zero4 = {0.f,0.f,0.f,0.f};
  f32x4 acc[FM][4];
  for (int i=0;i<FM;i++) for (int j=0;j<4;j++) acc[i][j] = zero4;

  const int nkt = K / BK;
  for (int kt=0; kt<nkt; ++kt){
    const int kb = kt*BK;
    {
      const unsigned short* Ab; int ld, kk;
      if (kb < K0){ Ab = A0; ld = ldA0; kk = kb; } else { Ab = A1; ld = ldA1; kk = kb - K0; }
      #pragma unroll
      for (int t=0;t<TA;t++){
        int c = t*256 + tid;
        int row = c >> 3, slot = c & 7;
        int srcs = slot ^ (row & 7);
        const unsigned short* g = Ab + (size_t)(m0+row)*ld + kk + srcs*8;
        load_lds16(g, (char*)As + (t*256 + w*64)*16);
      }
    }
    {
      #pragma unroll
      for (int t=0;t<4;t++){
        int c = t*256 + tid;
        int row = c >> 3, slot = c & 7;
        int srcs = slot ^ (row & 7);
        const unsigned short* g = Bt + (size_t)(n0+row)*K + kb + srcs*8;
        load_lds16(g, (char*)Bs + (t*256 + w*64)*16);
      }
    }
    asm volatile("s_waitcnt vmcnt(0)" ::: "memory");
    __syncthreads();
    #pragma unroll
    for (int kk=0; kk<2; ++kk){
      bf16x8 bfr[4];
      #pragma unroll
      for (int fn=0; fn<4; ++fn){
        int row  = wc*64 + fn*16 + (lane & 15);
        int slot = (kk*4 + (lane >> 4)) ^ (row & 7);
        bfr[fn] = *(const bf16x8*)(Bs + row*64 + slot*8);
      }
      #pragma unroll
      for (int fm=0; fm<FM; ++fm){
        int row  = wr*(BM/2) + fm*16 + (lane & 15);
        int slot = (kk*4 + (lane >> 4)) ^ (row & 7);
        bf16x8 afr = *(const bf16x8*)(As + row*64 + slot*8);
        #pragma unroll
        for (int fn=0; fn<4; ++fn){
          acc[fm][fn] = __builtin_amdgcn_mfma_f32_16x16x32_bf16(afr, bfr[fn], acc[fm][fn], 0, 0, 0);
        }
      }
    }
    __syncthreads();
  }
  #pragma unroll
  for (int fm=0; fm<FM; ++fm){
    int rbase = m0 + wr*(BM/2) + fm*16 + (lane >> 4)*4;
    #pragma unroll
    for (int fn=0; fn<4; ++fn){
      int col = n0 + wc*64 + fn*16 + (lane & 15);
      float b = bias[col];
      #pragma unroll
      for (int q=0;q<4;q++){
        float v = acc[fm][fn][q] + b;
        int row = rbase + q;
        if constexpr (RELU){
          v = v > 0.f ? v : 0.f;
          Cb[(size_t)row*ldC + col] = f2bf(v);
        } else {
          Cf[(size_t)row*ldC + col] = v;
        }
      }
    }
  }
}

// score[n] = sum_e dot4(w2_e, D[src_e][4g..]) + D[n][80+g]   (one node per wave, one edge per lane)
__global__ void k_score2(const float* __restrict__ D, const int* __restrict__ offs,
                         const int* __restrict__ cnt, const int* __restrict__ ssrc,
                         const float4* __restrict__ wts, const int* __restrict__ batch,
                         float* __restrict__ sc){
  int w = threadIdx.x >> 6, lane = threadIdx.x & 63;
  int n = blockIdx.x*4 + w;
  if (n >= NNODE) return;
  int g = batch[n];
  int o0 = offs[n*NRELS];
  int C  = offs[n*NRELS+7] + cnt[n*NRELS+7] - o0;
  float acc = 0.f;
  for (int j = lane; j < C; j += 64){
    int s = ssrc[o0 + j];
    float4 wv = wts[o0 + j];
    float4 dv = *(const float4*)(D + (size_t)s*128 + g*4);
    acc += wv.x*dv.x + wv.y*dv.y + wv.z*dv.z + wv.w*dv.w;
  }
  #pragma unroll
  for (int d=32; d; d>>=1) acc += __shfl_down(acc, d);
  if (lane == 0) sc[n] = acc + D[(size_t)n*128 + 80 + g];
}

__global__ void k_lsm(const float* __restrict__ sc, float* __restrict__ out){
  __shared__ float sb[1024];
  __shared__ float red[256];
  int g = blockIdx.x, t = threadIdx.x;
  float lm = -1e30f;
  for (int j=t; j<1024; j+=256){
    float v = (j < NPG) ? sc[g*NPG + j] : -1e30f;
    sb[j] = v; lm = fmaxf(lm, v);
  }
  red[t] = lm; __syncthreads();
  for (int off=128; off; off>>=1){ if (t < off) red[t] = fmaxf(red[t], red[t+off]); __syncthreads(); }
  float mx = red[0]; __syncthreads();
  float ls = 0.f;
  for (int j=t; j<1024; j+=256){ if (j < NPG) ls += expf(sb[j] - mx); }
  red[t] = ls; __syncthreads();
  for (int off=128; off; off>>=1){ if (t < off) red[t] += red[t+off]; __syncthreads(); }
  float lse = mx + logf(red[0]);
  for (int j=t; j<NPG; j+=256) out[g*NPG + j] = sb[j] - lse;
}

// ---------------- launch ----------------
extern "C" void kernel_launch(void* const* d_in, const int* in_sizes, int n_in,
                              void* d_out, int out_size, void* d_ws, size_t ws_size,
                              hipStream_t stream) {
  const float* x       = (const float*)d_in[0];
  const float* node_x  = (const float*)d_in[2];
  const int*   ei      = (const int*)d_in[3];
  const int*   et      = (const int*)d_in[4];
  const int*   batch   = (const int*)d_in[5];
  const float* comp1   = (const float*)d_in[7];
  const float* basis1  = (const float*)d_in[8];
  const float* root1   = (const float*)d_in[9];
  const float* bias1   = (const float*)d_in[10];
  const float* comp2   = (const float*)d_in[11];
  const float* basis2  = (const float*)d_in[12];
  const float* root2   = (const float*)d_in[13];
  const float* msg_w   = (const float*)d_in[15];
  const float* msg_b   = (const float*)d_in[16];
  float* out = (float*)d_out;

  char* p = (char*)d_ws;
  size_t off = 0;
  auto alloc = [&](size_t bytes) -> char* {
    char* r = p + off;
    off += (bytes + 255) & ~(size_t)255;
    return r;
  };
  int*            cnt    = (int*)alloc(NSEG*4);
  int*            offs   = (int*)alloc(NSEG*4);
  int*            cursor = (int*)alloc(NSEG*4);
  int*            ssrc   = (int*)alloc(NEDGE*4);
  float4*         wts1   = (float4*)alloc((size_t)NEDGE*16);
  float4*         wts2   = (float4*)alloc((size_t)NEDGE*16);
  int*            total  = (int*)alloc(256);
  float*          zbias  = (float*)alloc(128*4);
  unsigned short* B1t    = (unsigned short*)alloc((size_t)256*640*2);
  unsigned short* BtV    = (unsigned short*)alloc((size_t)128*256*2);
  unsigned short* xb     = (unsigned short*)alloc((size_t)MP*FEAT*2);
  unsigned short* s1     = (unsigned short*)alloc((size_t)MP*512*2);
  unsigned short* h      = (unsigned short*)alloc((size_t)MP*HID*2);
  float*          D      = (float*)alloc((size_t)MP*128*4);
  float*          sc     = (float*)alloc(NNODE*4);

  k_zero   <<<625, 256, 0, stream>>>(cnt, total, zbias, BtV);
  k_hist   <<<1250, 256, 0, stream>>>(ei, et, cnt);
  k_offsets<<<625, 256, 0, stream>>>(cnt, offs, cursor, total);
  k_scatter<<<1250, 256, 0, stream>>>(ei, et, cnt, cursor, comp1, comp2, ssrc, wts1, wts2);

  k_prep1<<<10640, 256, 0, stream>>>(node_x, xb, basis1, root1, B1t);
  k_prepV<<<NGRAPH, 256, 0, stream>>>(x, msg_w, msg_b, basis2, root2, BtV);

  k_agg1<<<2500, 256, 0, stream>>>(xb, offs, cnt, ssrc, wts1, s1);
  k_gemm<32, true><<<dim3(MP/32, 2), 256, 0, stream>>>(s1, 512, xb, FEAT, 512, 640,
                                                       B1t, bias1, h, nullptr, HID);
  k_gemm<32, false><<<dim3(MP/32, 1), 256, 0, stream>>>(h, HID, h, HID, HID, HID,
                                                        BtV, zbias, nullptr, D, 128);
  k_score2<<<5000, 256, 0, stream>>>(D, offs, cnt, ssrc, wts2, batch, sc);
  k_lsm  <<<NGRAPH, 256, 0, stream>>>(sc, out);
}

// Round 8
// 159.042 us; speedup vs baseline: 1.1043x; 1.1043x over previous
//
#include <hip/hip_runtime.h>
#include <hip/hip_bf16.h>

#define NEDGE 320000
#define NNODE 20000
#define MP    20096      // 157*128 padded rows
#define NRELS 8
#define NSEG  (NNODE*NRELS)   // 160000
#define FEAT  128
#define HID   256
#define EMB   128
#define NGRAPH 20
#define NPG   1000
#define NBASE 4

typedef __attribute__((ext_vector_type(4))) float f32x4;
typedef __attribute__((ext_vector_type(8))) __bf16 bf16x8;

static __device__ __forceinline__ float bf2f(unsigned short u){
  union { unsigned int i; float f; } v; v.i = ((unsigned int)u) << 16; return v.f;
}
static __device__ __forceinline__ unsigned short f2bf(float f){
  union { float f; unsigned int i; } v; v.f = f;
  unsigned int x = v.i;
  return (unsigned short)((x + 0x7fffu + ((x >> 16) & 1u)) >> 16);
}

__device__ __forceinline__ void load_lds16(const void* g, void* l){
  __builtin_amdgcn_global_load_lds((const __attribute__((address_space(1))) void*)g,
                                   (__attribute__((address_space(3))) void*)l, 16, 0, 0);
}

// ---------------- init ----------------
__global__ void k_zero(int* __restrict__ cnt, int* __restrict__ total, float* __restrict__ zbias){
  int i = blockIdx.x*256 + threadIdx.x;
  if (i < NSEG) cnt[i] = 0;
  if (i < 128) zbias[i] = 0.f;
  if (i == 0) *total = 0;
}

// ---------------- edge preprocessing ----------------
__global__ void k_hist(const int* __restrict__ ei, const int* __restrict__ et, int* __restrict__ cnt){
  int e = blockIdx.x*256 + threadIdx.x;
  if (e < NEDGE){
    int key = ei[NEDGE + e]*NRELS + et[e];
    atomicAdd(&cnt[key], 1);
  }
}

// Disjoint contiguous ranges per segment: wave prefix + one atomic per wave.
// Within a wave (64 consecutive keys) ranges are contiguous & key-ordered, so the
// 8 segments of any node n form ONE contiguous range.
__global__ void k_offsets(const int* __restrict__ cnt, int* __restrict__ offs,
                          int* __restrict__ cursor, int* __restrict__ total){
  int i = blockIdx.x*256 + threadIdx.x;
  int lane = threadIdx.x & 63;
  int c = (i < NSEG) ? cnt[i] : 0;
  int inc = c;
  #pragma unroll
  for (int d=1; d<64; d<<=1){
    int v = __shfl_up(inc, d);
    if (lane >= d) inc += v;
  }
  __shared__ int wbase[4];
  if (lane == 63) wbase[threadIdx.x>>6] = atomicAdd(total, inc);
  __syncthreads();
  if (i < NSEG){
    int base = wbase[threadIdx.x>>6] + inc - c;
    offs[i] = base;
    cursor[i] = base;
  }
}

// scatter sorted src + per-edge basis weights w_b = comp[r,b]/cnt(seg)
__global__ void k_scatter(const int* __restrict__ ei, const int* __restrict__ et,
                          const int* __restrict__ cnt, int* __restrict__ cursor,
                          const float* __restrict__ comp1, const float* __restrict__ comp2,
                          int* __restrict__ ssrc, float4* __restrict__ wts1, float4* __restrict__ wts2){
  int e = blockIdx.x*256 + threadIdx.x;
  if (e < NEDGE){
    int src = ei[e];
    int r = et[e];
    int key = ei[NEDGE + e]*NRELS + r;
    int pos = atomicAdd(&cursor[key], 1);
    float inv = 1.f / (float)cnt[key];
    ssrc[pos] = src;
    float4 w1, w2;
    w1.x = comp1[r*4+0]*inv; w1.y = comp1[r*4+1]*inv; w1.z = comp1[r*4+2]*inv; w1.w = comp1[r*4+3]*inv;
    w2.x = comp2[r*4+0]*inv; w2.y = comp2[r*4+1]*inv; w2.z = comp2[r*4+2]*inv; w2.w = comp2[r*4+3]*inv;
    wts1[pos] = w1;
    wts2[pos] = w2;
  }
}

// ---------------- layer1 basis aggregation ----------------
// half-wave (32 lanes x ushort4) per node, unroll 4 -> 8 gathers in flight per wave
// s1[n][b*128 + d] = sum_edges w1[b] * xb[src][d]
__global__ void k_agg1(const unsigned short* __restrict__ xb, const int* __restrict__ offs,
                       const int* __restrict__ cnt, const int* __restrict__ ssrc,
                       const float4* __restrict__ wts,
                       unsigned short* __restrict__ s1){
  int half = threadIdx.x >> 5, sl = threadIdx.x & 31;
  int n = blockIdx.x*8 + half;
  if (n >= NNODE) return;
  int o0 = offs[n*NRELS];
  int C  = offs[n*NRELS+7] + cnt[n*NRELS+7] - o0;
  const int* sp = ssrc + o0;
  const float4* wp = wts + o0;
  float u[NBASE][4] = {};
  int j = 0;
  for (; j+4 <= C; j += 4){
    int s0=sp[j], s1i=sp[j+1], s2i=sp[j+2], s3i=sp[j+3];
    float4 w0=wp[j], w1=wp[j+1], w2=wp[j+2], w3=wp[j+3];
    ushort4 v0 = *(const ushort4*)(xb + (size_t)s0*FEAT + sl*4);
    ushort4 v1 = *(const ushort4*)(xb + (size_t)s1i*FEAT + sl*4);
    ushort4 v2 = *(const ushort4*)(xb + (size_t)s2i*FEAT + sl*4);
    ushort4 v3 = *(const ushort4*)(xb + (size_t)s3i*FEAT + sl*4);
    float f0[4] = {bf2f(v0.x),bf2f(v0.y),bf2f(v0.z),bf2f(v0.w)};
    float f1[4] = {bf2f(v1.x),bf2f(v1.y),bf2f(v1.z),bf2f(v1.w)};
    float f2[4] = {bf2f(v2.x),bf2f(v2.y),bf2f(v2.z),bf2f(v2.w)};
    float f3[4] = {bf2f(v3.x),bf2f(v3.y),bf2f(v3.z),bf2f(v3.w)};
    #pragma unroll
    for (int b=0;b<NBASE;b++){
      float wb0=((const float*)&w0)[b], wb1=((const float*)&w1)[b];
      float wb2=((const float*)&w2)[b], wb3=((const float*)&w3)[b];
      #pragma unroll
      for (int k=0;k<4;k++)
        u[b][k] += wb0*f0[k] + wb1*f1[k] + wb2*f2[k] + wb3*f3[k];
    }
  }
  for (; j < C; ++j){
    int s = sp[j];
    float4 wv = wp[j];
    ushort4 v = *(const ushort4*)(xb + (size_t)s*FEAT + sl*4);
    float f[4] = {bf2f(v.x),bf2f(v.y),bf2f(v.z),bf2f(v.w)};
    #pragma unroll
    for (int b=0;b<NBASE;b++){
      float wb = ((const float*)&wv)[b];
      #pragma unroll
      for (int k=0;k<4;k++) u[b][k] += wb*f[k];
    }
  }
  #pragma unroll
  for (int b=0;b<NBASE;b++){
    ushort4 o4;
    o4.x = f2bf(u[b][0]); o4.y = f2bf(u[b][1]); o4.z = f2bf(u[b][2]); o4.w = f2bf(u[b][3]);
    *(ushort4*)(s1 + (size_t)n*(NBASE*FEAT) + b*FEAT + sl*4) = o4;
  }
}

// ---------------- fused weight prep: cvt node_x -> bf16  +  B1t gen ----------------
__global__ void k_prep1(const float* __restrict__ xin, unsigned short* __restrict__ xb,
                        const float* __restrict__ basis, const float* __restrict__ root,
                        unsigned short* __restrict__ Bt){
  int blk = blockIdx.x;
  if (blk < 10000){
    int i = blk*256 + threadIdx.x;
    if (i < NNODE*FEAT) xb[i] = f2bf(xin[i]);
  } else {
    int idx = (blk-10000)*256 + threadIdx.x;
    if (idx >= 256*640) return;
    int o = idx / 640, k = idx % 640;
    float v = (k < 512) ? basis[(size_t)k*256 + o] : root[(size_t)(k-512)*256 + o];
    Bt[(size_t)o*640 + k] = f2bf(v);
  }
}

// ---------------- head prep (coalesced trio) ----------------
__global__ void k_me(const float* __restrict__ x, const float* __restrict__ mw,
                     const float* __restrict__ mb, float* __restrict__ me){
  int id = blockIdx.x*256 + threadIdx.x;
  if (id >= NGRAPH*EMB) return;
  int g = id >> 7, e = id & 127;
  float s = mb[e];
  for (int i=0;i<HID;i++) s += x[g*HID + i] * mw[i*EMB + e];
  me[id] = s;
}

// v[g][k] = dot(Bcat2[k,:], me[g,:]) ; Bcat2 = [basis2 (1024 rows) ; root2 (256 rows)]
__global__ void k_v(const float* __restrict__ basis2, const float* __restrict__ root2,
                    const float* __restrict__ me, float* __restrict__ v){
  int w = threadIdx.x >> 6, lane = threadIdx.x & 63;
  int id = blockIdx.x*4 + w;
  if (id >= NGRAPH*1280) return;
  int g = id / 1280, k = id % 1280;
  const float* row = (k < 1024) ? (basis2 + (size_t)k*EMB) : (root2 + (size_t)(k-1024)*EMB);
  float2 a = *(const float2*)(row + lane*2);
  float2 m = *(const float2*)(me + g*EMB + lane*2);
  float p = a.x*m.x + a.y*m.y;
  #pragma unroll
  for (int d=32; d; d>>=1) p += __shfl_down(p, d);
  if (lane == 0) v[(size_t)g*1280 + k] = p;
}

// BtV [128 c][256 k] bf16: c=4g+b -> v[g][b*256+k]; c=80+g -> v[g][1024+k]; else 0
__global__ void k_packV(const float* __restrict__ v, unsigned short* __restrict__ BtV){
  int idx = blockIdx.x*256 + threadIdx.x;
  if (idx >= 128*256) return;
  int c = idx >> 8, k = idx & 255;
  float val = 0.f;
  if (c < 80)        val = v[(size_t)(c>>2)*1280 + (c&3)*256 + k];
  else if (c < 100)  val = v[(size_t)(c-80)*1280 + 1024 + k];
  BtV[idx] = f2bf(val);
}

// ---------------- GEMM: C[M x 128tile] = [A0|A1] @ Bt^T ----------------
template<int BM, bool RELU>
__global__ __launch_bounds__(256, 2)
void k_gemm(const unsigned short* __restrict__ A0, int ldA0,
            const unsigned short* __restrict__ A1, int ldA1, int K0, int K,
            const unsigned short* __restrict__ Bt,
            const float* __restrict__ bias,
            unsigned short* __restrict__ Cb, float* __restrict__ Cf, int ldC)
{
  constexpr int BK = 64;
  constexpr int FM = BM/32;
  constexpr int TA = BM*8/256;
  __shared__ __align__(16) unsigned short As[BM*BK];
  __shared__ __align__(16) unsigned short Bs[128*BK];

  const int tid  = threadIdx.x;
  const int w    = tid >> 6, lane = tid & 63;
  const int wr   = w >> 1,  wc   = w & 1;
  const int m0   = blockIdx.x * BM;
  const int n0   = blockIdx.y * 128;

  const f32x4 zero4 = {0.f,0.f,0.f,0.f};
  f32x4 acc[FM][4];
  for (int i=0;i<FM;i++) for (int j=0;j<4;j++) acc[i][j] = zero4;

  const int nkt = K / BK;
  for (int kt=0; kt<nkt; ++kt){
    const int kb = kt*BK;
    {
      const unsigned short* Ab; int ld, kk;
      if (kb < K0){ Ab = A0; ld = ldA0; kk = kb; } else { Ab = A1; ld = ldA1; kk = kb - K0; }
      #pragma unroll
      for (int t=0;t<TA;t++){
        int c = t*256 + tid;
        int row = c >> 3, slot = c & 7;
        int srcs = slot ^ (row & 7);
        const unsigned short* g = Ab + (size_t)(m0+row)*ld + kk + srcs*8;
        load_lds16(g, (char*)As + (t*256 + w*64)*16);
      }
    }
    {
      #pragma unroll
      for (int t=0;t<4;t++){
        int c = t*256 + tid;
        int row = c >> 3, slot = c & 7;
        int srcs = slot ^ (row & 7);
        const unsigned short* g = Bt + (size_t)(n0+row)*K + kb + srcs*8;
        load_lds16(g, (char*)Bs + (t*256 + w*64)*16);
      }
    }
    asm volatile("s_waitcnt vmcnt(0)" ::: "memory");
    __syncthreads();
    #pragma unroll
    for (int kk=0; kk<2; ++kk){
      bf16x8 bfr[4];
      #pragma unroll
      for (int fn=0; fn<4; ++fn){
        int row  = wc*64 + fn*16 + (lane & 15);
        int slot = (kk*4 + (lane >> 4)) ^ (row & 7);
        bfr[fn] = *(const bf16x8*)(Bs + row*64 + slot*8);
      }
      #pragma unroll
      for (int fm=0; fm<FM; ++fm){
        int row  = wr*(BM/2) + fm*16 + (lane & 15);
        int slot = (kk*4 + (lane >> 4)) ^ (row & 7);
        bf16x8 afr = *(const bf16x8*)(As + row*64 + slot*8);
        #pragma unroll
        for (int fn=0; fn<4; ++fn){
          acc[fm][fn] = __builtin_amdgcn_mfma_f32_16x16x32_bf16(afr, bfr[fn], acc[fm][fn], 0, 0, 0);
        }
      }
    }
    __syncthreads();
  }
  #pragma unroll
  for (int fm=0; fm<FM; ++fm){
    int rbase = m0 + wr*(BM/2) + fm*16 + (lane >> 4)*4;
    #pragma unroll
    for (int fn=0; fn<4; ++fn){
      int col = n0 + wc*64 + fn*16 + (lane & 15);
      float b = bias[col];
      #pragma unroll
      for (int q=0;q<4;q++){
        float v = acc[fm][fn][q] + b;
        int row = rbase + q;
        if constexpr (RELU){
          v = v > 0.f ? v : 0.f;
          Cb[(size_t)row*ldC + col] = f2bf(v);
        } else {
          Cf[(size_t)row*ldC + col] = v;
        }
      }
    }
  }
}

// score[n] = sum_e dot4(w2_e, D[src_e][4g..]) + D[n][80+g]   (one node per wave, one edge per lane)
__global__ void k_score2(const float* __restrict__ D, const int* __restrict__ offs,
                         const int* __restrict__ cnt, const int* __restrict__ ssrc,
                         const float4* __restrict__ wts, const int* __restrict__ batch,
                         float* __restrict__ sc){
  int w = threadIdx.x >> 6, lane = threadIdx.x & 63;
  int n = blockIdx.x*4 + w;
  if (n >= NNODE) return;
  int g = batch[n];
  int o0 = offs[n*NRELS];
  int C  = offs[n*NRELS+7] + cnt[n*NRELS+7] - o0;
  float acc = 0.f;
  for (int j = lane; j < C; j += 64){
    int s = ssrc[o0 + j];
    float4 wv = wts[o0 + j];
    float4 dv = *(const float4*)(D + (size_t)s*128 + g*4);
    acc += wv.x*dv.x + wv.y*dv.y + wv.z*dv.z + wv.w*dv.w;
  }
  #pragma unroll
  for (int d=32; d; d>>=1) acc += __shfl_down(acc, d);
  if (lane == 0) sc[n] = acc + D[(size_t)n*128 + 80 + g];
}

__global__ void k_lsm(const float* __restrict__ sc, float* __restrict__ out){
  __shared__ float sb[1024];
  __shared__ float red[256];
  int g = blockIdx.x, t = threadIdx.x;
  float lm = -1e30f;
  for (int j=t; j<1024; j+=256){
    float v = (j < NPG) ? sc[g*NPG + j] : -1e30f;
    sb[j] = v; lm = fmaxf(lm, v);
  }
  red[t] = lm; __syncthreads();
  for (int off=128; off; off>>=1){ if (t < off) red[t] = fmaxf(red[t], red[t+off]); __syncthreads(); }
  float mx = red[0]; __syncthreads();
  float ls = 0.f;
  for (int j=t; j<1024; j+=256){ if (j < NPG) ls += expf(sb[j] - mx); }
  red[t] = ls; __syncthreads();
  for (int off=128; off; off>>=1){ if (t < off) red[t] += red[t+off]; __syncthreads(); }
  float lse = mx + logf(red[0]);
  for (int j=t; j<NPG; j+=256) out[g*NPG + j] = sb[j] - lse;
}

// ---------------- launch ----------------
extern "C" void kernel_launch(void* const* d_in, const int* in_sizes, int n_in,
                              void* d_out, int out_size, void* d_ws, size_t ws_size,
                              hipStream_t stream) {
  const float* x       = (const float*)d_in[0];
  const float* node_x  = (const float*)d_in[2];
  const int*   ei      = (const int*)d_in[3];
  const int*   et      = (const int*)d_in[4];
  const int*   batch   = (const int*)d_in[5];
  const float* comp1   = (const float*)d_in[7];
  const float* basis1  = (const float*)d_in[8];
  const float* root1   = (const float*)d_in[9];
  const float* bias1   = (const float*)d_in[10];
  const float* comp2   = (const float*)d_in[11];
  const float* basis2  = (const float*)d_in[12];
  const float* root2   = (const float*)d_in[13];
  const float* msg_w   = (const float*)d_in[15];
  const float* msg_b   = (const float*)d_in[16];
  float* out = (float*)d_out;

  char* p = (char*)d_ws;
  size_t off = 0;
  auto alloc = [&](size_t bytes) -> char* {
    char* r = p + off;
    off += (bytes + 255) & ~(size_t)255;
    return r;
  };
  int*            cnt    = (int*)alloc(NSEG*4);
  int*            offs   = (int*)alloc(NSEG*4);
  int*            cursor = (int*)alloc(NSEG*4);
  int*            ssrc   = (int*)alloc(NEDGE*4);
  float4*         wts1   = (float4*)alloc((size_t)NEDGE*16);
  float4*         wts2   = (float4*)alloc((size_t)NEDGE*16);
  int*            total  = (int*)alloc(256);
  float*          zbias  = (float*)alloc(128*4);
  unsigned short* B1t    = (unsigned short*)alloc((size_t)256*640*2);
  unsigned short* BtV    = (unsigned short*)alloc((size_t)128*256*2);
  float*          me     = (float*)alloc(NGRAPH*EMB*4);
  float*          v      = (float*)alloc((size_t)NGRAPH*1280*4);
  unsigned short* xb     = (unsigned short*)alloc((size_t)MP*FEAT*2);
  unsigned short* s1     = (unsigned short*)alloc((size_t)MP*512*2);
  unsigned short* h      = (unsigned short*)alloc((size_t)MP*HID*2);
  float*          D      = (float*)alloc((size_t)MP*128*4);
  float*          sc     = (float*)alloc(NNODE*4);

  k_zero   <<<625, 256, 0, stream>>>(cnt, total, zbias);
  k_hist   <<<1250, 256, 0, stream>>>(ei, et, cnt);
  k_offsets<<<625, 256, 0, stream>>>(cnt, offs, cursor, total);
  k_scatter<<<1250, 256, 0, stream>>>(ei, et, cnt, cursor, comp1, comp2, ssrc, wts1, wts2);

  k_prep1<<<10640, 256, 0, stream>>>(node_x, xb, basis1, root1, B1t);
  k_me <<<10, 256, 0, stream>>>(x, msg_w, msg_b, me);
  k_v  <<<6400, 256, 0, stream>>>(basis2, root2, me, v);
  k_packV<<<128, 256, 0, stream>>>(v, BtV);

  k_agg1<<<2500, 256, 0, stream>>>(xb, offs, cnt, ssrc, wts1, s1);
  k_gemm<32, true><<<dim3(MP/32, 2), 256, 0, stream>>>(s1, 512, xb, FEAT, 512, 640,
                                                       B1t, bias1, h, nullptr, HID);
  k_gemm<32, false><<<dim3(MP/32, 1), 256, 0, stream>>>(h, HID, h, HID, HID, HID,
                                                        BtV, zbias, nullptr, D, 128);
  k_score2<<<5000, 256, 0, stream>>>(D, offs, cnt, ssrc, wts2, batch, sc);
  k_lsm  <<<NGRAPH, 256, 0, stream>>>(sc, out);
}

// Round 9
// 150.669 us; speedup vs baseline: 1.1657x; 1.0556x over previous
//
#include <hip/hip_runtime.h>
#include <hip/hip_bf16.h>

#define NEDGE 320000
#define NNODE 20000
#define MP    20096      // 157*128 padded rows
#define NRELS 8
#define NSEG  (NNODE*NRELS)   // 160000
#define FEAT  128
#define HID   256
#define EMB   128
#define NGRAPH 20
#define NPG   1000
#define NBASE 4

typedef __attribute__((ext_vector_type(4))) float f32x4;
typedef __attribute__((ext_vector_type(8))) __bf16 bf16x8;
typedef __attribute__((ext_vector_type(8))) unsigned short u16x8;

static __device__ __forceinline__ float bf2f(unsigned short u){
  union { unsigned int i; float f; } v; v.i = ((unsigned int)u) << 16; return v.f;
}
static __device__ __forceinline__ unsigned short f2bf(float f){
  union { float f; unsigned int i; } v; v.f = f;
  unsigned int x = v.i;
  return (unsigned short)((x + 0x7fffu + ((x >> 16) & 1u)) >> 16);
}

__device__ __forceinline__ void load_lds16(const void* g, void* l){
  __builtin_amdgcn_global_load_lds((const __attribute__((address_space(1))) void*)g,
                                   (__attribute__((address_space(3))) void*)l, 16, 0, 0);
}

// ---------------- fused init + me ----------------
// blocks 0..624: zero cnt/total/zbias ; blocks 625..634: me[g][e]
__global__ void k_zeroMe(int* __restrict__ cnt, int* __restrict__ total, float* __restrict__ zbias,
                         const float* __restrict__ x, const float* __restrict__ mw,
                         const float* __restrict__ mb, float* __restrict__ me){
  int blk = blockIdx.x;
  if (blk < 625){
    int i = blk*256 + threadIdx.x;
    if (i < NSEG) cnt[i] = 0;
    if (i < 128) zbias[i] = 0.f;
    if (i == 0) *total = 0;
  } else {
    int id = (blk-625)*256 + threadIdx.x;
    if (id >= NGRAPH*EMB) return;
    int g = id >> 7, e = id & 127;
    float s = mb[e];
    for (int i=0;i<HID;i++) s += x[g*HID + i] * mw[i*EMB + e];
    me[id] = s;
  }
}

// ---------------- edge preprocessing ----------------
__global__ void k_hist(const int* __restrict__ ei, const int* __restrict__ et, int* __restrict__ cnt){
  int e = blockIdx.x*256 + threadIdx.x;
  if (e < NEDGE){
    int key = ei[NEDGE + e]*NRELS + et[e];
    atomicAdd(&cnt[key], 1);
  }
}

// Disjoint contiguous ranges per segment: wave prefix + one atomic per wave.
// Within a wave (64 consecutive keys) ranges are contiguous & key-ordered, so the
// 8 segments of any node n form ONE contiguous range.
__global__ void k_offsets(const int* __restrict__ cnt, int* __restrict__ offs,
                          int* __restrict__ cursor, int* __restrict__ total){
  int i = blockIdx.x*256 + threadIdx.x;
  int lane = threadIdx.x & 63;
  int c = (i < NSEG) ? cnt[i] : 0;
  int inc = c;
  #pragma unroll
  for (int d=1; d<64; d<<=1){
    int v = __shfl_up(inc, d);
    if (lane >= d) inc += v;
  }
  __shared__ int wbase[4];
  if (lane == 63) wbase[threadIdx.x>>6] = atomicAdd(total, inc);
  __syncthreads();
  if (i < NSEG){
    int base = wbase[threadIdx.x>>6] + inc - c;
    offs[i] = base;
    cursor[i] = base;
  }
}

// scatter sorted src + per-edge basis weights w_b = comp[r,b]/cnt(seg)
__global__ void k_scatter(const int* __restrict__ ei, const int* __restrict__ et,
                          const int* __restrict__ cnt, int* __restrict__ cursor,
                          const float* __restrict__ comp1, const float* __restrict__ comp2,
                          int* __restrict__ ssrc, float4* __restrict__ wts1, float4* __restrict__ wts2){
  int e = blockIdx.x*256 + threadIdx.x;
  if (e < NEDGE){
    int src = ei[e];
    int r = et[e];
    int key = ei[NEDGE + e]*NRELS + r;
    int pos = atomicAdd(&cursor[key], 1);
    float inv = 1.f / (float)cnt[key];
    ssrc[pos] = src;
    float4 w1, w2;
    w1.x = comp1[r*4+0]*inv; w1.y = comp1[r*4+1]*inv; w1.z = comp1[r*4+2]*inv; w1.w = comp1[r*4+3]*inv;
    w2.x = comp2[r*4+0]*inv; w2.y = comp2[r*4+1]*inv; w2.z = comp2[r*4+2]*inv; w2.w = comp2[r*4+3]*inv;
    wts1[pos] = w1;
    wts2[pos] = w2;
  }
}

// ---------------- fused weight prep: cvt node_x->bf16 + B1t gen + v ----------------
// blocks 0..9999: xb ; 10000..10639: B1t ; 10640..17039: v[g][k]
__global__ void k_prep1v(const float* __restrict__ xin, unsigned short* __restrict__ xb,
                         const float* __restrict__ basis, const float* __restrict__ root,
                         unsigned short* __restrict__ Bt,
                         const float* __restrict__ basis2, const float* __restrict__ root2,
                         const float* __restrict__ me, float* __restrict__ v){
  int blk = blockIdx.x;
  if (blk < 10000){
    int i = blk*256 + threadIdx.x;
    if (i < NNODE*FEAT) xb[i] = f2bf(xin[i]);
  } else if (blk < 10640){
    int idx = (blk-10000)*256 + threadIdx.x;
    if (idx >= 256*640) return;
    int o = idx / 640, k = idx % 640;
    float val = (k < 512) ? basis[(size_t)k*256 + o] : root[(size_t)(k-512)*256 + o];
    Bt[(size_t)o*640 + k] = f2bf(val);
  } else {
    int w = threadIdx.x >> 6, lane = threadIdx.x & 63;
    int id = (blk-10640)*4 + w;
    if (id >= NGRAPH*1280) return;
    int g = id / 1280, k = id % 1280;
    const float* row = (k < 1024) ? (basis2 + (size_t)k*EMB) : (root2 + (size_t)(k-1024)*EMB);
    float2 a = *(const float2*)(row + lane*2);
    float2 m = *(const float2*)(me + g*EMB + lane*2);
    float p = a.x*m.x + a.y*m.y;
    #pragma unroll
    for (int d=32; d; d>>=1) p += __shfl_down(p, d);
    if (lane == 0) v[(size_t)g*1280 + k] = p;
  }
}

// ---------------- layer1 aggregation (16-lane groups, u16x8, unroll 4) + packV ----------------
// blocks 0..1249: s1[n][b*128+d] = sum_edges w1[b]*xb[src][d]  (16 nodes/block)
// blocks 1250..1377: BtV pack
__global__ void k_agg1(const unsigned short* __restrict__ xb, const int* __restrict__ offs,
                       const int* __restrict__ cnt, const int* __restrict__ ssrc,
                       const float4* __restrict__ wts, unsigned short* __restrict__ s1,
                       const float* __restrict__ v, unsigned short* __restrict__ BtV){
  if (blockIdx.x >= 1250){
    int idx = (blockIdx.x-1250)*256 + threadIdx.x;
    if (idx >= 128*256) return;
    int c = idx >> 8, k = idx & 255;
    float val = 0.f;
    if (c < 80)        val = v[(size_t)(c>>2)*1280 + (c&3)*256 + k];
    else if (c < 100)  val = v[(size_t)(c-80)*1280 + 1024 + k];
    BtV[idx] = f2bf(val);
    return;
  }
  int grp = threadIdx.x >> 4, sl = threadIdx.x & 15;
  int n = blockIdx.x*16 + grp;
  int o0 = offs[n*NRELS];
  int C  = offs[n*NRELS+7] + cnt[n*NRELS+7] - o0;
  const int* sp = ssrc + o0;
  const float4* wp = wts + o0;
  float u[NBASE][8] = {};
  int j = 0;
  for (; j+4 <= C; j += 4){
    int s0=sp[j], s1i=sp[j+1], s2i=sp[j+2], s3i=sp[j+3];
    float4 w0=wp[j], w1=wp[j+1], w2=wp[j+2], w3=wp[j+3];
    u16x8 v0 = *(const u16x8*)(xb + (size_t)s0*FEAT + sl*8);
    u16x8 v1 = *(const u16x8*)(xb + (size_t)s1i*FEAT + sl*8);
    u16x8 v2 = *(const u16x8*)(xb + (size_t)s2i*FEAT + sl*8);
    u16x8 v3 = *(const u16x8*)(xb + (size_t)s3i*FEAT + sl*8);
    #pragma unroll
    for (int b=0;b<NBASE;b++){
      float wb0=((const float*)&w0)[b], wb1=((const float*)&w1)[b];
      float wb2=((const float*)&w2)[b], wb3=((const float*)&w3)[b];
      #pragma unroll
      for (int k=0;k<8;k++)
        u[b][k] += wb0*bf2f(v0[k]) + wb1*bf2f(v1[k]) + wb2*bf2f(v2[k]) + wb3*bf2f(v3[k]);
    }
  }
  for (; j < C; ++j){
    int s = sp[j];
    float4 wv = wp[j];
    u16x8 vv = *(const u16x8*)(xb + (size_t)s*FEAT + sl*8);
    #pragma unroll
    for (int b=0;b<NBASE;b++){
      float wb = ((const float*)&wv)[b];
      #pragma unroll
      for (int k=0;k<8;k++) u[b][k] += wb*bf2f(vv[k]);
    }
  }
  #pragma unroll
  for (int b=0;b<NBASE;b++){
    u16x8 o8;
    #pragma unroll
    for (int k=0;k<8;k++) o8[k] = f2bf(u[b][k]);
    *(u16x8*)(s1 + (size_t)n*(NBASE*FEAT) + b*FEAT + sl*8) = o8;
  }
}

// ---------------- GEMM: C[M x 128tile] = [A0|A1] @ Bt^T ----------------
template<int BM, bool RELU>
__global__ __launch_bounds__(256, 2)
void k_gemm(const unsigned short* __restrict__ A0, int ldA0,
            const unsigned short* __restrict__ A1, int ldA1, int K0, int K,
            const unsigned short* __restrict__ Bt,
            const float* __restrict__ bias,
            unsigned short* __restrict__ Cb, float* __restrict__ Cf, int ldC)
{
  constexpr int BK = 64;
  constexpr int FM = BM/32;
  constexpr int TA = BM*8/256;
  __shared__ __align__(16) unsigned short As[BM*BK];
  __shared__ __align__(16) unsigned short Bs[128*BK];

  const int tid  = threadIdx.x;
  const int w    = tid >> 6, lane = tid & 63;
  const int wr   = w >> 1,  wc   = w & 1;
  const int m0   = blockIdx.x * BM;
  const int n0   = blockIdx.y * 128;

  const f32x4 zero4 = {0.f,0.f,0.f,0.f};
  f32x4 acc[FM][4];
  for (int i=0;i<FM;i++) for (int j=0;j<4;j++) acc[i][j] = zero4;

  const int nkt = K / BK;
  for (int kt=0; kt<nkt; ++kt){
    const int kb = kt*BK;
    {
      const unsigned short* Ab; int ld, kk;
      if (kb < K0){ Ab = A0; ld = ldA0; kk = kb; } else { Ab = A1; ld = ldA1; kk = kb - K0; }
      #pragma unroll
      for (int t=0;t<TA;t++){
        int c = t*256 + tid;
        int row = c >> 3, slot = c & 7;
        int srcs = slot ^ (row & 7);
        const unsigned short* g = Ab + (size_t)(m0+row)*ld + kk + srcs*8;
        load_lds16(g, (char*)As + (t*256 + w*64)*16);
      }
    }
    {
      #pragma unroll
      for (int t=0;t<4;t++){
        int c = t*256 + tid;
        int row = c >> 3, slot = c & 7;
        int srcs = slot ^ (row & 7);
        const unsigned short* g = Bt + (size_t)(n0+row)*K + kb + srcs*8;
        load_lds16(g, (char*)Bs + (t*256 + w*64)*16);
      }
    }
    asm volatile("s_waitcnt vmcnt(0)" ::: "memory");
    __syncthreads();
    #pragma unroll
    for (int kk=0; kk<2; ++kk){
      bf16x8 bfr[4];
      #pragma unroll
      for (int fn=0; fn<4; ++fn){
        int row  = wc*64 + fn*16 + (lane & 15);
        int slot = (kk*4 + (lane >> 4)) ^ (row & 7);
        bfr[fn] = *(const bf16x8*)(Bs + row*64 + slot*8);
      }
      #pragma unroll
      for (int fm=0; fm<FM; ++fm){
        int row  = wr*(BM/2) + fm*16 + (lane & 15);
        int slot = (kk*4 + (lane >> 4)) ^ (row & 7);
        bf16x8 afr = *(const bf16x8*)(As + row*64 + slot*8);
        #pragma unroll
        for (int fn=0; fn<4; ++fn){
          acc[fm][fn] = __builtin_amdgcn_mfma_f32_16x16x32_bf16(afr, bfr[fn], acc[fm][fn], 0, 0, 0);
        }
      }
    }
    __syncthreads();
  }
  #pragma unroll
  for (int fm=0; fm<FM; ++fm){
    int rbase = m0 + wr*(BM/2) + fm*16 + (lane >> 4)*4;
    #pragma unroll
    for (int fn=0; fn<4; ++fn){
      int col = n0 + wc*64 + fn*16 + (lane & 15);
      float b = bias[col];
      #pragma unroll
      for (int q=0;q<4;q++){
        float v = acc[fm][fn][q] + b;
        int row = rbase + q;
        if constexpr (RELU){
          v = v > 0.f ? v : 0.f;
          Cb[(size_t)row*ldC + col] = f2bf(v);
        } else {
          Cf[(size_t)row*ldC + col] = v;
        }
      }
    }
  }
}

// score[n] = sum_e dot4(w2_e, D[src_e][4g..]) + D[n][80+g]   (one node per wave, one edge per lane)
__global__ void k_score2(const float* __restrict__ D, const int* __restrict__ offs,
                         const int* __restrict__ cnt, const int* __restrict__ ssrc,
                         const float4* __restrict__ wts, const int* __restrict__ batch,
                         float* __restrict__ sc){
  int w = threadIdx.x >> 6, lane = threadIdx.x & 63;
  int n = blockIdx.x*4 + w;
  if (n >= NNODE) return;
  int g = batch[n];
  int o0 = offs[n*NRELS];
  int C  = offs[n*NRELS+7] + cnt[n*NRELS+7] - o0;
  float acc = 0.f;
  for (int j = lane; j < C; j += 64){
    int s = ssrc[o0 + j];
    float4 wv = wts[o0 + j];
    float4 dv = *(const float4*)(D + (size_t)s*128 + g*4);
    acc += wv.x*dv.x + wv.y*dv.y + wv.z*dv.z + wv.w*dv.w;
  }
  #pragma unroll
  for (int d=32; d; d>>=1) acc += __shfl_down(acc, d);
  if (lane == 0) sc[n] = acc + D[(size_t)n*128 + 80 + g];
}

__global__ void k_lsm(const float* __restrict__ sc, float* __restrict__ out){
  __shared__ float sb[1024];
  __shared__ float red[256];
  int g = blockIdx.x, t = threadIdx.x;
  float lm = -1e30f;
  for (int j=t; j<1024; j+=256){
    float v = (j < NPG) ? sc[g*NPG + j] : -1e30f;
    sb[j] = v; lm = fmaxf(lm, v);
  }
  red[t] = lm; __syncthreads();
  for (int off=128; off; off>>=1){ if (t < off) red[t] = fmaxf(red[t], red[t+off]); __syncthreads(); }
  float mx = red[0]; __syncthreads();
  float ls = 0.f;
  for (int j=t; j<1024; j+=256){ if (j < NPG) ls += expf(sb[j] - mx); }
  red[t] = ls; __syncthreads();
  for (int off=128; off; off>>=1){ if (t < off) red[t] += red[t+off]; __syncthreads(); }
  float lse = mx + logf(red[0]);
  for (int j=t; j<NPG; j+=256) out[g*NPG + j] = sb[j] - lse;
}

// ---------------- launch ----------------
extern "C" void kernel_launch(void* const* d_in, const int* in_sizes, int n_in,
                              void* d_out, int out_size, void* d_ws, size_t ws_size,
                              hipStream_t stream) {
  const float* x       = (const float*)d_in[0];
  const float* node_x  = (const float*)d_in[2];
  const int*   ei      = (const int*)d_in[3];
  const int*   et      = (const int*)d_in[4];
  const int*   batch   = (const int*)d_in[5];
  const float* comp1   = (const float*)d_in[7];
  const float* basis1  = (const float*)d_in[8];
  const float* root1   = (const float*)d_in[9];
  const float* bias1   = (const float*)d_in[10];
  const float* comp2   = (const float*)d_in[11];
  const float* basis2  = (const float*)d_in[12];
  const float* root2   = (const float*)d_in[13];
  const float* msg_w   = (const float*)d_in[15];
  const float* msg_b   = (const float*)d_in[16];
  float* out = (float*)d_out;

  char* p = (char*)d_ws;
  size_t off = 0;
  auto alloc = [&](size_t bytes) -> char* {
    char* r = p + off;
    off += (bytes + 255) & ~(size_t)255;
    return r;
  };
  int*            cnt    = (int*)alloc(NSEG*4);
  int*            offs   = (int*)alloc(NSEG*4);
  int*            cursor = (int*)alloc(NSEG*4);
  int*            ssrc   = (int*)alloc(NEDGE*4);
  float4*         wts1   = (float4*)alloc((size_t)NEDGE*16);
  float4*         wts2   = (float4*)alloc((size_t)NEDGE*16);
  int*            total  = (int*)alloc(256);
  float*          zbias  = (float*)alloc(128*4);
  unsigned short* B1t    = (unsigned short*)alloc((size_t)256*640*2);
  unsigned short* BtV    = (unsigned short*)alloc((size_t)128*256*2);
  float*          me     = (float*)alloc(NGRAPH*EMB*4);
  float*          v      = (float*)alloc((size_t)NGRAPH*1280*4);
  unsigned short* xb     = (unsigned short*)alloc((size_t)MP*FEAT*2);
  unsigned short* s1     = (unsigned short*)alloc((size_t)MP*512*2);
  unsigned short* h      = (unsigned short*)alloc((size_t)MP*HID*2);
  float*          D      = (float*)alloc((size_t)MP*128*4);
  float*          sc     = (float*)alloc(NNODE*4);

  k_zeroMe <<<635, 256, 0, stream>>>(cnt, total, zbias, x, msg_w, msg_b, me);
  k_hist   <<<1250, 256, 0, stream>>>(ei, et, cnt);
  k_offsets<<<625, 256, 0, stream>>>(cnt, offs, cursor, total);
  k_scatter<<<1250, 256, 0, stream>>>(ei, et, cnt, cursor, comp1, comp2, ssrc, wts1, wts2);

  k_prep1v<<<17040, 256, 0, stream>>>(node_x, xb, basis1, root1, B1t, basis2, root2, me, v);

  k_agg1<<<1378, 256, 0, stream>>>(xb, offs, cnt, ssrc, wts1, s1, v, BtV);
  k_gemm<32, true><<<dim3(MP/32, 2), 256, 0, stream>>>(s1, 512, xb, FEAT, 512, 640,
                                                       B1t, bias1, h, nullptr, HID);
  k_gemm<32, false><<<dim3(MP/32, 1), 256, 0, stream>>>(h, HID, h, HID, HID, HID,
                                                        BtV, zbias, nullptr, D, 128);
  k_score2<<<5000, 256, 0, stream>>>(D, offs, cnt, ssrc, wts2, batch, sc);
  k_lsm  <<<NGRAPH, 256, 0, stream>>>(sc, out);
}

// Round 10
// 144.882 us; speedup vs baseline: 1.2123x; 1.0399x over previous
//
#include <hip/hip_runtime.h>
#include <hip/hip_bf16.h>

#define NEDGE 320000
#define NNODE 20000
#define MP    20096      // 157*128 padded rows
#define NRELS 8
#define NSEG  (NNODE*NRELS)   // 160000
#define FEAT  128
#define HID   256
#define EMB   128
#define NGRAPH 20
#define NPG   1000
#define NBASE 4

typedef __attribute__((ext_vector_type(4))) float f32x4;
typedef __attribute__((ext_vector_type(8))) __bf16 bf16x8;
typedef __attribute__((ext_vector_type(8))) unsigned short u16x8;

static __device__ __forceinline__ float bf2f(unsigned short u){
  union { unsigned int i; float f; } v; v.i = ((unsigned int)u) << 16; return v.f;
}
static __device__ __forceinline__ unsigned short f2bf(float f){
  union { float f; unsigned int i; } v; v.f = f;
  unsigned int x = v.i;
  return (unsigned short)((x + 0x7fffu + ((x >> 16) & 1u)) >> 16);
}

__device__ __forceinline__ void load_lds16(const void* g, void* l){
  __builtin_amdgcn_global_load_lds((const __attribute__((address_space(1))) void*)g,
                                   (__attribute__((address_space(3))) void*)l, 16, 0, 0);
}

// ---------------- fused init + me ----------------
__global__ void k_zeroMe(int* __restrict__ cnt, int* __restrict__ total, float* __restrict__ zbias,
                         const float* __restrict__ x, const float* __restrict__ mw,
                         const float* __restrict__ mb, float* __restrict__ me){
  int blk = blockIdx.x;
  if (blk < 625){
    int i = blk*256 + threadIdx.x;
    if (i < NSEG) cnt[i] = 0;
    if (i < 128) zbias[i] = 0.f;
    if (i == 0) *total = 0;
  } else {
    int id = (blk-625)*256 + threadIdx.x;
    if (id >= NGRAPH*EMB) return;
    int g = id >> 7, e = id & 127;
    float s = mb[e];
    for (int i=0;i<HID;i++) s += x[g*HID + i] * mw[i*EMB + e];
    me[id] = s;
  }
}

// ---------------- fused hist + weight prep (independent work overlaps atomics) ----------------
// blocks 0..1249: hist ; 1250..11249: xb cvt ; 11250..11889: B1t ; 11890..18289: v
__global__ void k_histPrep(const int* __restrict__ ei, const int* __restrict__ et, int* __restrict__ cnt,
                           const float* __restrict__ xin, unsigned short* __restrict__ xb,
                           const float* __restrict__ basis, const float* __restrict__ root,
                           unsigned short* __restrict__ Bt,
                           const float* __restrict__ basis2, const float* __restrict__ root2,
                           const float* __restrict__ me, float* __restrict__ v){
  int blk = blockIdx.x;
  if (blk < 1250){
    int e = blk*256 + threadIdx.x;
    if (e < NEDGE){
      int key = ei[NEDGE + e]*NRELS + et[e];
      atomicAdd(&cnt[key], 1);
    }
  } else if (blk < 11250){
    int i = (blk-1250)*256 + threadIdx.x;
    if (i < NNODE*FEAT) xb[i] = f2bf(xin[i]);
  } else if (blk < 11890){
    int idx = (blk-11250)*256 + threadIdx.x;
    if (idx >= 256*640) return;
    int o = idx / 640, k = idx % 640;
    float val = (k < 512) ? basis[(size_t)k*256 + o] : root[(size_t)(k-512)*256 + o];
    Bt[(size_t)o*640 + k] = f2bf(val);
  } else {
    int w = threadIdx.x >> 6, lane = threadIdx.x & 63;
    int id = (blk-11890)*4 + w;
    if (id >= NGRAPH*1280) return;
    int g = id / 1280, k = id % 1280;
    const float* row = (k < 1024) ? (basis2 + (size_t)k*EMB) : (root2 + (size_t)(k-1024)*EMB);
    float2 a = *(const float2*)(row + lane*2);
    float2 m = *(const float2*)(me + g*EMB + lane*2);
    float p = a.x*m.x + a.y*m.y;
    #pragma unroll
    for (int d=32; d; d>>=1) p += __shfl_down(p, d);
    if (lane == 0) v[(size_t)g*1280 + k] = p;
  }
}

// Disjoint contiguous ranges per segment: wave prefix + one atomic per wave.
__global__ void k_offsets(const int* __restrict__ cnt, int* __restrict__ offs,
                          int* __restrict__ cursor, int* __restrict__ total){
  int i = blockIdx.x*256 + threadIdx.x;
  int lane = threadIdx.x & 63;
  int c = (i < NSEG) ? cnt[i] : 0;
  int inc = c;
  #pragma unroll
  for (int d=1; d<64; d<<=1){
    int vv = __shfl_up(inc, d);
    if (lane >= d) inc += vv;
  }
  __shared__ int wbase[4];
  if (lane == 63) wbase[threadIdx.x>>6] = atomicAdd(total, inc);
  __syncthreads();
  if (i < NSEG){
    int base = wbase[threadIdx.x>>6] + inc - c;
    offs[i] = base;
    cursor[i] = base;
  }
}

// scatter: single packed u32 per edge: src(15b) | r(3b) | cnt(14b)
__global__ void k_scatter(const int* __restrict__ ei, const int* __restrict__ et,
                          const int* __restrict__ cnt, int* __restrict__ cursor,
                          unsigned int* __restrict__ spk){
  int e = blockIdx.x*256 + threadIdx.x;
  if (e < NEDGE){
    int src = ei[e];
    int r = et[e];
    int key = ei[NEDGE + e]*NRELS + r;
    int pos = atomicAdd(&cursor[key], 1);
    int c = cnt[key]; if (c > 16383) c = 16383;
    spk[pos] = (unsigned int)src | ((unsigned int)r << 15) | ((unsigned int)c << 18);
  }
}

// ---------------- layer1 aggregation (16-lane groups, packed edges) + packV ----------------
// blocks 0..1249: s1[n][b*128+d] = sum_edges comp1[r][b]/c * xb[src][d]  (16 nodes/block)
// blocks 1250..1377: BtV pack
__global__ void k_agg1(const unsigned short* __restrict__ xb, const int* __restrict__ offs,
                       const int* __restrict__ cnt, const unsigned int* __restrict__ spk,
                       const float* __restrict__ comp1, unsigned short* __restrict__ s1,
                       const float* __restrict__ v, unsigned short* __restrict__ BtV){
  if (blockIdx.x >= 1250){
    int idx = (blockIdx.x-1250)*256 + threadIdx.x;
    if (idx >= 128*256) return;
    int c = idx >> 8, k = idx & 255;
    float val = 0.f;
    if (c < 80)        val = v[(size_t)(c>>2)*1280 + (c&3)*256 + k];
    else if (c < 100)  val = v[(size_t)(c-80)*1280 + 1024 + k];
    BtV[idx] = f2bf(val);
    return;
  }
  __shared__ float c1s[32];
  if (threadIdx.x < 32) c1s[threadIdx.x] = comp1[threadIdx.x];
  __syncthreads();
  int grp = threadIdx.x >> 4, sl = threadIdx.x & 15;
  int n = blockIdx.x*16 + grp;
  int o0 = offs[n*NRELS];
  int C  = offs[n*NRELS+7] + cnt[n*NRELS+7] - o0;
  const unsigned int* pp = spk + o0;
  float u[NBASE][8] = {};
  int j = 0;
  for (; j+4 <= C; j += 4){
    unsigned int p0=pp[j], p1=pp[j+1], p2=pp[j+2], p3=pp[j+3];
    u16x8 v0 = *(const u16x8*)(xb + (size_t)(p0 & 0x7FFF)*FEAT + sl*8);
    u16x8 v1 = *(const u16x8*)(xb + (size_t)(p1 & 0x7FFF)*FEAT + sl*8);
    u16x8 v2 = *(const u16x8*)(xb + (size_t)(p2 & 0x7FFF)*FEAT + sl*8);
    u16x8 v3 = *(const u16x8*)(xb + (size_t)(p3 & 0x7FFF)*FEAT + sl*8);
    float i0 = __builtin_amdgcn_rcpf((float)(p0 >> 18));
    float i1 = __builtin_amdgcn_rcpf((float)(p1 >> 18));
    float i2 = __builtin_amdgcn_rcpf((float)(p2 >> 18));
    float i3 = __builtin_amdgcn_rcpf((float)(p3 >> 18));
    const float* c0 = c1s + ((p0 >> 15) & 7)*4;
    const float* c1 = c1s + ((p1 >> 15) & 7)*4;
    const float* c2 = c1s + ((p2 >> 15) & 7)*4;
    const float* c3 = c1s + ((p3 >> 15) & 7)*4;
    #pragma unroll
    for (int b=0;b<NBASE;b++){
      float wb0=c0[b]*i0, wb1=c1[b]*i1, wb2=c2[b]*i2, wb3=c3[b]*i3;
      #pragma unroll
      for (int k=0;k<8;k++)
        u[b][k] += wb0*bf2f(v0[k]) + wb1*bf2f(v1[k]) + wb2*bf2f(v2[k]) + wb3*bf2f(v3[k]);
    }
  }
  for (; j < C; ++j){
    unsigned int pk = pp[j];
    u16x8 vv = *(const u16x8*)(xb + (size_t)(pk & 0x7FFF)*FEAT + sl*8);
    float inv = __builtin_amdgcn_rcpf((float)(pk >> 18));
    const float* cr = c1s + ((pk >> 15) & 7)*4;
    #pragma unroll
    for (int b=0;b<NBASE;b++){
      float wb = cr[b]*inv;
      #pragma unroll
      for (int k=0;k<8;k++) u[b][k] += wb*bf2f(vv[k]);
    }
  }
  #pragma unroll
  for (int b=0;b<NBASE;b++){
    u16x8 o8;
    #pragma unroll
    for (int k=0;k<8;k++) o8[k] = f2bf(u[b][k]);
    *(u16x8*)(s1 + (size_t)n*(NBASE*FEAT) + b*FEAT + sl*8) = o8;
  }
}

// ---------------- GEMM: C[M x 128tile] = [A0|A1] @ Bt^T ----------------
template<int BM, bool RELU>
__global__ __launch_bounds__(256, 2)
void k_gemm(const unsigned short* __restrict__ A0, int ldA0,
            const unsigned short* __restrict__ A1, int ldA1, int K0, int K,
            const unsigned short* __restrict__ Bt,
            const float* __restrict__ bias,
            unsigned short* __restrict__ Cb, float* __restrict__ Cf, int ldC)
{
  constexpr int BK = 64;
  constexpr int FM = BM/32;
  constexpr int TA = BM*8/256;
  __shared__ __align__(16) unsigned short As[BM*BK];
  __shared__ __align__(16) unsigned short Bs[128*BK];

  const int tid  = threadIdx.x;
  const int w    = tid >> 6, lane = tid & 63;
  const int wr   = w >> 1,  wc   = w & 1;
  const int m0   = blockIdx.x * BM;
  const int n0   = blockIdx.y * 128;

  const f32x4 zero4 = {0.f,0.f,0.f,0.f};
  f32x4 acc[FM][4];
  for (int i=0;i<FM;i++) for (int j=0;j<4;j++) acc[i][j] = zero4;

  const int nkt = K / BK;
  for (int kt=0; kt<nkt; ++kt){
    const int kb = kt*BK;
    {
      const unsigned short* Ab; int ld, kk;
      if (kb < K0){ Ab = A0; ld = ldA0; kk = kb; } else { Ab = A1; ld = ldA1; kk = kb - K0; }
      #pragma unroll
      for (int t=0;t<TA;t++){
        int c = t*256 + tid;
        int row = c >> 3, slot = c & 7;
        int srcs = slot ^ (row & 7);
        const unsigned short* g = Ab + (size_t)(m0+row)*ld + kk + srcs*8;
        load_lds16(g, (char*)As + (t*256 + w*64)*16);
      }
    }
    {
      #pragma unroll
      for (int t=0;t<4;t++){
        int c = t*256 + tid;
        int row = c >> 3, slot = c & 7;
        int srcs = slot ^ (row & 7);
        const unsigned short* g = Bt + (size_t)(n0+row)*K + kb + srcs*8;
        load_lds16(g, (char*)Bs + (t*256 + w*64)*16);
      }
    }
    asm volatile("s_waitcnt vmcnt(0)" ::: "memory");
    __syncthreads();
    #pragma unroll
    for (int kk=0; kk<2; ++kk){
      bf16x8 bfr[4];
      #pragma unroll
      for (int fn=0; fn<4; ++fn){
        int row  = wc*64 + fn*16 + (lane & 15);
        int slot = (kk*4 + (lane >> 4)) ^ (row & 7);
        bfr[fn] = *(const bf16x8*)(Bs + row*64 + slot*8);
      }
      #pragma unroll
      for (int fm=0; fm<FM; ++fm){
        int row  = wr*(BM/2) + fm*16 + (lane & 15);
        int slot = (kk*4 + (lane >> 4)) ^ (row & 7);
        bf16x8 afr = *(const bf16x8*)(As + row*64 + slot*8);
        #pragma unroll
        for (int fn=0; fn<4; ++fn){
          acc[fm][fn] = __builtin_amdgcn_mfma_f32_16x16x32_bf16(afr, bfr[fn], acc[fm][fn], 0, 0, 0);
        }
      }
    }
    __syncthreads();
  }
  #pragma unroll
  for (int fm=0; fm<FM; ++fm){
    int rbase = m0 + wr*(BM/2) + fm*16 + (lane >> 4)*4;
    #pragma unroll
    for (int fn=0; fn<4; ++fn){
      int col = n0 + wc*64 + fn*16 + (lane & 15);
      float b = bias[col];
      #pragma unroll
      for (int q=0;q<4;q++){
        float v = acc[fm][fn][q] + b;
        int row = rbase + q;
        if constexpr (RELU){
          v = v > 0.f ? v : 0.f;
          Cb[(size_t)row*ldC + col] = f2bf(v);
        } else {
          Cf[(size_t)row*ldC + col] = v;
        }
      }
    }
  }
}

// score[n] = sum_e inv_e * dot4(comp2[r_e], D[src_e][4g..]) + D[n][80+g]
__global__ void k_score2(const float* __restrict__ D, const int* __restrict__ offs,
                         const int* __restrict__ cnt, const unsigned int* __restrict__ spk,
                         const float* __restrict__ comp2, const int* __restrict__ batch,
                         float* __restrict__ sc){
  __shared__ float4 c2s[8];
  if (threadIdx.x < 8) c2s[threadIdx.x] = ((const float4*)comp2)[threadIdx.x];
  __syncthreads();
  int w = threadIdx.x >> 6, lane = threadIdx.x & 63;
  int n = blockIdx.x*4 + w;
  if (n >= NNODE) return;
  int g = batch[n];
  int o0 = offs[n*NRELS];
  int C  = offs[n*NRELS+7] + cnt[n*NRELS+7] - o0;
  float acc = 0.f;
  for (int j = lane; j < C; j += 64){
    unsigned int pk = spk[o0 + j];
    int s = pk & 0x7FFF;
    float inv = __builtin_amdgcn_rcpf((float)(pk >> 18));
    float4 dv = *(const float4*)(D + (size_t)s*128 + g*4);
    float4 cw = c2s[(pk >> 15) & 7];
    acc += inv*(cw.x*dv.x + cw.y*dv.y + cw.z*dv.z + cw.w*dv.w);
  }
  #pragma unroll
  for (int d=32; d; d>>=1) acc += __shfl_down(acc, d);
  if (lane == 0) sc[n] = acc + D[(size_t)n*128 + 80 + g];
}

__global__ void k_lsm(const float* __restrict__ sc, float* __restrict__ out){
  __shared__ float sb[1024];
  __shared__ float red[256];
  int g = blockIdx.x, t = threadIdx.x;
  float lm = -1e30f;
  for (int j=t; j<1024; j+=256){
    float v = (j < NPG) ? sc[g*NPG + j] : -1e30f;
    sb[j] = v; lm = fmaxf(lm, v);
  }
  red[t] = lm; __syncthreads();
  for (int off=128; off; off>>=1){ if (t < off) red[t] = fmaxf(red[t], red[t+off]); __syncthreads(); }
  float mx = red[0]; __syncthreads();
  float ls = 0.f;
  for (int j=t; j<1024; j+=256){ if (j < NPG) ls += expf(sb[j] - mx); }
  red[t] = ls; __syncthreads();
  for (int off=128; off; off>>=1){ if (t < off) red[t] += red[t+off]; __syncthreads(); }
  float lse = mx + logf(red[0]);
  for (int j=t; j<NPG; j+=256) out[g*NPG + j] = sb[j] - lse;
}

// ---------------- launch ----------------
extern "C" void kernel_launch(void* const* d_in, const int* in_sizes, int n_in,
                              void* d_out, int out_size, void* d_ws, size_t ws_size,
                              hipStream_t stream) {
  const float* x       = (const float*)d_in[0];
  const float* node_x  = (const float*)d_in[2];
  const int*   ei      = (const int*)d_in[3];
  const int*   et      = (const int*)d_in[4];
  const int*   batch   = (const int*)d_in[5];
  const float* comp1   = (const float*)d_in[7];
  const float* basis1  = (const float*)d_in[8];
  const float* root1   = (const float*)d_in[9];
  const float* bias1   = (const float*)d_in[10];
  const float* comp2   = (const float*)d_in[11];
  const float* basis2  = (const float*)d_in[12];
  const float* root2   = (const float*)d_in[13];
  const float* msg_w   = (const float*)d_in[15];
  const float* msg_b   = (const float*)d_in[16];
  float* out = (float*)d_out;

  char* p = (char*)d_ws;
  size_t off = 0;
  auto alloc = [&](size_t bytes) -> char* {
    char* r = p + off;
    off += (bytes + 255) & ~(size_t)255;
    return r;
  };
  int*            cnt    = (int*)alloc(NSEG*4);
  int*            offs   = (int*)alloc(NSEG*4);
  int*            cursor = (int*)alloc(NSEG*4);
  unsigned int*   spk    = (unsigned int*)alloc(NEDGE*4);
  int*            total  = (int*)alloc(256);
  float*          zbias  = (float*)alloc(128*4);
  unsigned short* B1t    = (unsigned short*)alloc((size_t)256*640*2);
  unsigned short* BtV    = (unsigned short*)alloc((size_t)128*256*2);
  float*          me     = (float*)alloc(NGRAPH*EMB*4);
  float*          v      = (float*)alloc((size_t)NGRAPH*1280*4);
  unsigned short* xb     = (unsigned short*)alloc((size_t)MP*FEAT*2);
  unsigned short* s1     = (unsigned short*)alloc((size_t)MP*512*2);
  unsigned short* h      = (unsigned short*)alloc((size_t)MP*HID*2);
  float*          D      = (float*)alloc((size_t)MP*128*4);
  float*          sc     = (float*)alloc(NNODE*4);

  k_zeroMe  <<<635, 256, 0, stream>>>(cnt, total, zbias, x, msg_w, msg_b, me);
  k_histPrep<<<18290, 256, 0, stream>>>(ei, et, cnt, node_x, xb, basis1, root1, B1t,
                                        basis2, root2, me, v);
  k_offsets <<<625, 256, 0, stream>>>(cnt, offs, cursor, total);
  k_scatter <<<1250, 256, 0, stream>>>(ei, et, cnt, cursor, spk);

  k_agg1<<<1378, 256, 0, stream>>>(xb, offs, cnt, spk, comp1, s1, v, BtV);
  k_gemm<32, true><<<dim3(MP/32, 2), 256, 0, stream>>>(s1, 512, xb, FEAT, 512, 640,
                                                       B1t, bias1, h, nullptr, HID);
  k_gemm<32, false><<<dim3(MP/32, 1), 256, 0, stream>>>(h, HID, h, HID, HID, HID,
                                                        BtV, zbias, nullptr, D, 128);
  k_score2<<<5000, 256, 0, stream>>>(D, offs, cnt, spk, comp2, batch, sc);
  k_lsm  <<<NGRAPH, 256, 0, stream>>>(sc, out);
}

// Round 11
// 138.913 us; speedup vs baseline: 1.2643x; 1.0430x over previous
//
#include <hip/hip_runtime.h>
#include <hip/hip_bf16.h>

#define NEDGE 320000
#define NNODE 20000
#define MP    20096      // 157*128 padded rows
#define NRELS 8
#define NSEG  (NNODE*NRELS)   // 160000
#define FEAT  128
#define HID   256
#define EMB   128
#define NGRAPH 20
#define NPG   1000
#define NBASE 4

typedef __attribute__((ext_vector_type(4))) float f32x4;
typedef __attribute__((ext_vector_type(8))) __bf16 bf16x8;
typedef __attribute__((ext_vector_type(8))) unsigned short u16x8;

static __device__ __forceinline__ float bf2f(unsigned short u){
  union { unsigned int i; float f; } v; v.i = ((unsigned int)u) << 16; return v.f;
}
static __device__ __forceinline__ unsigned short f2bf(float f){
  union { float f; unsigned int i; } v; v.f = f;
  unsigned int x = v.i;
  return (unsigned short)((x + 0x7fffu + ((x >> 16) & 1u)) >> 16);
}

__device__ __forceinline__ void load_lds16(const void* g, void* l){
  __builtin_amdgcn_global_load_lds((const __attribute__((address_space(1))) void*)g,
                                   (__attribute__((address_space(3))) void*)l, 16, 0, 0);
}

// ---------------- fused init + me ----------------
__global__ void k_zeroMe(int* __restrict__ cnt, int* __restrict__ total,
                         const float* __restrict__ x, const float* __restrict__ mw,
                         const float* __restrict__ mb, float* __restrict__ me){
  int blk = blockIdx.x;
  if (blk < 625){
    int i = blk*256 + threadIdx.x;
    if (i < NSEG) cnt[i] = 0;
    if (i == 0) *total = 0;
  } else {
    int id = (blk-625)*256 + threadIdx.x;
    if (id >= NGRAPH*EMB) return;
    int g = id >> 7, e = id & 127;
    float s = mb[e];
    for (int i=0;i<HID;i++) s += x[g*HID + i] * mw[i*EMB + e];
    me[id] = s;
  }
}

// ---------------- fused hist + weight prep ----------------
// blocks 0..1249: hist ; 1250..11249: xb cvt ; 11250..11889: B1t ; 11890..18289: v
__global__ void k_histPrep(const int* __restrict__ ei, const int* __restrict__ et, int* __restrict__ cnt,
                           const float* __restrict__ xin, unsigned short* __restrict__ xb,
                           const float* __restrict__ basis, const float* __restrict__ root,
                           unsigned short* __restrict__ Bt,
                           const float* __restrict__ basis2, const float* __restrict__ root2,
                           const float* __restrict__ me, float* __restrict__ v){
  int blk = blockIdx.x;
  if (blk < 1250){
    int e = blk*256 + threadIdx.x;
    if (e < NEDGE){
      int key = ei[NEDGE + e]*NRELS + et[e];
      atomicAdd(&cnt[key], 1);
    }
  } else if (blk < 11250){
    int i = (blk-1250)*256 + threadIdx.x;
    if (i < NNODE*FEAT) xb[i] = f2bf(xin[i]);
  } else if (blk < 11890){
    int idx = (blk-11250)*256 + threadIdx.x;
    if (idx >= 256*640) return;
    int o = idx / 640, k = idx % 640;
    float val = (k < 512) ? basis[(size_t)k*256 + o] : root[(size_t)(k-512)*256 + o];
    Bt[(size_t)o*640 + k] = f2bf(val);
  } else {
    int w = threadIdx.x >> 6, lane = threadIdx.x & 63;
    int id = (blk-11890)*4 + w;
    if (id >= NGRAPH*1280) return;
    int g = id / 1280, k = id % 1280;
    const float* row = (k < 1024) ? (basis2 + (size_t)k*EMB) : (root2 + (size_t)(k-1024)*EMB);
    float2 a = *(const float2*)(row + lane*2);
    float2 m = *(const float2*)(me + g*EMB + lane*2);
    float p = a.x*m.x + a.y*m.y;
    #pragma unroll
    for (int d=32; d; d>>=1) p += __shfl_down(p, d);
    if (lane == 0) v[(size_t)g*1280 + k] = p;
  }
}

// Disjoint contiguous ranges per segment: wave prefix + one atomic per wave.
__global__ void k_offsets(const int* __restrict__ cnt, int* __restrict__ offs,
                          int* __restrict__ cursor, int* __restrict__ total){
  int i = blockIdx.x*256 + threadIdx.x;
  int lane = threadIdx.x & 63;
  int c = (i < NSEG) ? cnt[i] : 0;
  int inc = c;
  #pragma unroll
  for (int d=1; d<64; d<<=1){
    int vv = __shfl_up(inc, d);
    if (lane >= d) inc += vv;
  }
  __shared__ int wbase[4];
  if (lane == 63) wbase[threadIdx.x>>6] = atomicAdd(total, inc);
  __syncthreads();
  if (i < NSEG){
    int base = wbase[threadIdx.x>>6] + inc - c;
    offs[i] = base;
    cursor[i] = base;
  }
}

// scatter: single packed u32 per edge: src(15b) | r(3b) | cnt(14b)
__global__ void k_scatter(const int* __restrict__ ei, const int* __restrict__ et,
                          const int* __restrict__ cnt, int* __restrict__ cursor,
                          unsigned int* __restrict__ spk){
  int e = blockIdx.x*256 + threadIdx.x;
  if (e < NEDGE){
    int src = ei[e];
    int r = et[e];
    int key = ei[NEDGE + e]*NRELS + r;
    int pos = atomicAdd(&cursor[key], 1);
    int c = cnt[key]; if (c > 16383) c = 16383;
    spk[pos] = (unsigned int)src | ((unsigned int)r << 15) | ((unsigned int)c << 18);
  }
}

// ---------------- layer1 aggregation (16-lane groups, packed edges) + packV ----------------
__global__ void k_agg1(const unsigned short* __restrict__ xb, const int* __restrict__ offs,
                       const int* __restrict__ cnt, const unsigned int* __restrict__ spk,
                       const float* __restrict__ comp1, unsigned short* __restrict__ s1,
                       const float* __restrict__ v, unsigned short* __restrict__ BtV){
  if (blockIdx.x >= 1250){
    int idx = (blockIdx.x-1250)*256 + threadIdx.x;
    if (idx >= 128*256) return;
    int c = idx >> 8, k = idx & 255;
    float val = 0.f;
    if (c < 80)        val = v[(size_t)(c>>2)*1280 + (c&3)*256 + k];
    else if (c < 100)  val = v[(size_t)(c-80)*1280 + 1024 + k];
    BtV[idx] = f2bf(val);
    return;
  }
  __shared__ float c1s[32];
  if (threadIdx.x < 32) c1s[threadIdx.x] = comp1[threadIdx.x];
  __syncthreads();
  int grp = threadIdx.x >> 4, sl = threadIdx.x & 15;
  int n = blockIdx.x*16 + grp;
  int o0 = offs[n*NRELS];
  int C  = offs[n*NRELS+7] + cnt[n*NRELS+7] - o0;
  const unsigned int* pp = spk + o0;
  float u[NBASE][8] = {};
  int j = 0;
  for (; j+4 <= C; j += 4){
    unsigned int p0=pp[j], p1=pp[j+1], p2=pp[j+2], p3=pp[j+3];
    u16x8 v0 = *(const u16x8*)(xb + (size_t)(p0 & 0x7FFF)*FEAT + sl*8);
    u16x8 v1 = *(const u16x8*)(xb + (size_t)(p1 & 0x7FFF)*FEAT + sl*8);
    u16x8 v2 = *(const u16x8*)(xb + (size_t)(p2 & 0x7FFF)*FEAT + sl*8);
    u16x8 v3 = *(const u16x8*)(xb + (size_t)(p3 & 0x7FFF)*FEAT + sl*8);
    float i0 = __builtin_amdgcn_rcpf((float)(p0 >> 18));
    float i1 = __builtin_amdgcn_rcpf((float)(p1 >> 18));
    float i2 = __builtin_amdgcn_rcpf((float)(p2 >> 18));
    float i3 = __builtin_amdgcn_rcpf((float)(p3 >> 18));
    const float* c0 = c1s + ((p0 >> 15) & 7)*4;
    const float* c1 = c1s + ((p1 >> 15) & 7)*4;
    const float* c2 = c1s + ((p2 >> 15) & 7)*4;
    const float* c3 = c1s + ((p3 >> 15) & 7)*4;
    #pragma unroll
    for (int b=0;b<NBASE;b++){
      float wb0=c0[b]*i0, wb1=c1[b]*i1, wb2=c2[b]*i2, wb3=c3[b]*i3;
      #pragma unroll
      for (int k=0;k<8;k++)
        u[b][k] += wb0*bf2f(v0[k]) + wb1*bf2f(v1[k]) + wb2*bf2f(v2[k]) + wb3*bf2f(v3[k]);
    }
  }
  for (; j < C; ++j){
    unsigned int pk = pp[j];
    u16x8 vv = *(const u16x8*)(xb + (size_t)(pk & 0x7FFF)*FEAT + sl*8);
    float inv = __builtin_amdgcn_rcpf((float)(pk >> 18));
    const float* cr = c1s + ((pk >> 15) & 7)*4;
    #pragma unroll
    for (int b=0;b<NBASE;b++){
      float wb = cr[b]*inv;
      #pragma unroll
      for (int k=0;k<8;k++) u[b][k] += wb*bf2f(vv[k]);
    }
  }
  #pragma unroll
  for (int b=0;b<NBASE;b++){
    u16x8 o8;
    #pragma unroll
    for (int k=0;k<8;k++) o8[k] = f2bf(u[b][k]);
    *(u16x8*)(s1 + (size_t)n*(NBASE*FEAT) + b*FEAT + sl*8) = o8;
  }
}

// ---------------- fused GEMM: h-tile (32x256, regs) -> relu -> LDS bf16 -> D-tile (32x128) ----------------
// stage1: h = relu([s1|xb] @ B1t^T + bias1), K=640. stage2: D = h @ BtV^T, K=256.
__global__ __launch_bounds__(256, 2)
void k_gemmHD(const unsigned short* __restrict__ A0,   // s1 [MP][512]
              const unsigned short* __restrict__ A1,   // xb [MP][128]
              const unsigned short* __restrict__ B1t,  // [256][640]
              const unsigned short* __restrict__ BtV,  // [128][256]
              const float* __restrict__ bias1,
              float* __restrict__ D)                   // [MP][128]
{
  __shared__ __align__(16) unsigned short As[32*64];     // 4 KB
  __shared__ __align__(16) unsigned short Bs[256*64];    // 32 KB (stage1; first 16KB reused stage2)
  __shared__ __align__(16) unsigned short hs[32*256];    // 16 KB

  const int tid = threadIdx.x;
  const int w = tid >> 6, lane = tid & 63;
  const int wr = w >> 1, wc = w & 1;
  const int m0 = blockIdx.x * 32;

  f32x4 acc[8];
  #pragma unroll
  for (int i=0;i<8;i++) acc[i] = (f32x4){0.f,0.f,0.f,0.f};

  // ---- stage 1 ----
  for (int kt=0; kt<10; ++kt){
    const int kb = kt*64;
    {
      const unsigned short* Ab; int ld, kk0;
      if (kb < 512){ Ab = A0; ld = 512; kk0 = kb; } else { Ab = A1; ld = 128; kk0 = kb-512; }
      int row = tid >> 3, slot = tid & 7;
      int srcs = slot ^ (row & 7);
      load_lds16(Ab + (size_t)(m0+row)*ld + kk0 + srcs*8, (char*)As + (w*64)*16);
    }
    #pragma unroll
    for (int t=0;t<8;t++){
      int c = t*256 + tid, row = c >> 3, slot = c & 7;
      int srcs = slot ^ (row & 7);
      load_lds16(B1t + (size_t)row*640 + kb + srcs*8, (char*)Bs + (t*256 + w*64)*16);
    }
    asm volatile("s_waitcnt vmcnt(0)" ::: "memory");
    __syncthreads();
    #pragma unroll
    for (int kk=0;kk<2;++kk){
      int arow = wr*16 + (lane & 15);
      int aslot = (kk*4 + (lane >> 4)) ^ (arow & 7);
      bf16x8 afr = *(const bf16x8*)(As + arow*64 + aslot*8);
      #pragma unroll
      for (int fn=0;fn<8;++fn){
        int brow = wc*128 + fn*16 + (lane & 15);
        int bslot = (kk*4 + (lane >> 4)) ^ (brow & 7);
        bf16x8 bfr = *(const bf16x8*)(Bs + brow*64 + bslot*8);
        acc[fn] = __builtin_amdgcn_mfma_f32_16x16x32_bf16(afr, bfr, acc[fn], 0, 0, 0);
      }
    }
    __syncthreads();
  }
  // h tile -> LDS (bias + relu, bf16, octet XOR swizzle on 8-slot groups)
  #pragma unroll
  for (int fn=0;fn<8;++fn){
    int col = wc*128 + fn*16 + (lane & 15);
    float b = bias1[col];
    int s = col >> 3;
    #pragma unroll
    for (int q=0;q<4;q++){
      int row = wr*16 + (lane >> 4)*4 + q;
      float val = acc[fn][q] + b;
      val = val > 0.f ? val : 0.f;
      int p = (s & ~7) | ((s & 7) ^ (row & 7));
      hs[row*256 + p*8 + (col & 7)] = f2bf(val);
    }
  }
  __syncthreads();

  // ---- stage 2 ----
  f32x4 acc2[4];
  #pragma unroll
  for (int i=0;i<4;i++) acc2[i] = (f32x4){0.f,0.f,0.f,0.f};
  for (int kt=0; kt<4; ++kt){
    const int kb = kt*64;
    #pragma unroll
    for (int t=0;t<4;t++){
      int c = t*256 + tid, row = c >> 3, slot = c & 7;
      int srcs = slot ^ (row & 7);
      load_lds16(BtV + (size_t)row*256 + kb + srcs*8, (char*)Bs + (t*256 + w*64)*16);
    }
    asm volatile("s_waitcnt vmcnt(0)" ::: "memory");
    __syncthreads();
    #pragma unroll
    for (int kk=0;kk<2;++kk){
      int arow = wr*16 + (lane & 15);
      int slog = kt*8 + kk*4 + (lane >> 4);
      int ap = (slog & ~7) | ((slog & 7) ^ (arow & 7));
      bf16x8 afr = *(const bf16x8*)(hs + arow*256 + ap*8);
      #pragma unroll
      for (int fn=0;fn<4;++fn){
        int brow = wc*64 + fn*16 + (lane & 15);
        int bslot = (kk*4 + (lane >> 4)) ^ (brow & 7);
        bf16x8 bfr = *(const bf16x8*)(Bs + brow*64 + bslot*8);
        acc2[fn] = __builtin_amdgcn_mfma_f32_16x16x32_bf16(afr, bfr, acc2[fn], 0, 0, 0);
      }
    }
    __syncthreads();
  }
  #pragma unroll
  for (int fn=0;fn<4;++fn){
    int col = wc*64 + fn*16 + (lane & 15);
    #pragma unroll
    for (int q=0;q<4;q++){
      int row = m0 + wr*16 + (lane >> 4)*4 + q;
      D[(size_t)row*128 + col] = acc2[fn][q];
    }
  }
}

// score[n] = sum_e inv_e * dot4(comp2[r_e], D[src_e][4g..]) + D[n][80+g]
__global__ void k_score2(const float* __restrict__ D, const int* __restrict__ offs,
                         const int* __restrict__ cnt, const unsigned int* __restrict__ spk,
                         const float* __restrict__ comp2, const int* __restrict__ batch,
                         float* __restrict__ sc){
  __shared__ float4 c2s[8];
  if (threadIdx.x < 8) c2s[threadIdx.x] = ((const float4*)comp2)[threadIdx.x];
  __syncthreads();
  int w = threadIdx.x >> 6, lane = threadIdx.x & 63;
  int n = blockIdx.x*4 + w;
  if (n >= NNODE) return;
  int g = batch[n];
  int o0 = offs[n*NRELS];
  int C  = offs[n*NRELS+7] + cnt[n*NRELS+7] - o0;
  float acc = 0.f;
  for (int j = lane; j < C; j += 64){
    unsigned int pk = spk[o0 + j];
    int s = pk & 0x7FFF;
    float inv = __builtin_amdgcn_rcpf((float)(pk >> 18));
    float4 dv = *(const float4*)(D + (size_t)s*128 + g*4);
    float4 cw = c2s[(pk >> 15) & 7];
    acc += inv*(cw.x*dv.x + cw.y*dv.y + cw.z*dv.z + cw.w*dv.w);
  }
  #pragma unroll
  for (int d=32; d; d>>=1) acc += __shfl_down(acc, d);
  if (lane == 0) sc[n] = acc + D[(size_t)n*128 + 80 + g];
}

__global__ void k_lsm(const float* __restrict__ sc, float* __restrict__ out){
  __shared__ float sb[1024];
  __shared__ float red[256];
  int g = blockIdx.x, t = threadIdx.x;
  float lm = -1e30f;
  for (int j=t; j<1024; j+=256){
    float v = (j < NPG) ? sc[g*NPG + j] : -1e30f;
    sb[j] = v; lm = fmaxf(lm, v);
  }
  red[t] = lm; __syncthreads();
  for (int off=128; off; off>>=1){ if (t < off) red[t] = fmaxf(red[t], red[t+off]); __syncthreads(); }
  float mx = red[0]; __syncthreads();
  float ls = 0.f;
  for (int j=t; j<1024; j+=256){ if (j < NPG) ls += expf(sb[j] - mx); }
  red[t] = ls; __syncthreads();
  for (int off=128; off; off>>=1){ if (t < off) red[t] += red[t+off]; __syncthreads(); }
  float lse = mx + logf(red[0]);
  for (int j=t; j<NPG; j+=256) out[g*NPG + j] = sb[j] - lse;
}

// ---------------- launch ----------------
extern "C" void kernel_launch(void* const* d_in, const int* in_sizes, int n_in,
                              void* d_out, int out_size, void* d_ws, size_t ws_size,
                              hipStream_t stream) {
  const float* x       = (const float*)d_in[0];
  const float* node_x  = (const float*)d_in[2];
  const int*   ei      = (const int*)d_in[3];
  const int*   et      = (const int*)d_in[4];
  const int*   batch   = (const int*)d_in[5];
  const float* comp1   = (const float*)d_in[7];
  const float* basis1  = (const float*)d_in[8];
  const float* root1   = (const float*)d_in[9];
  const float* bias1   = (const float*)d_in[10];
  const float* comp2   = (const float*)d_in[11];
  const float* basis2  = (const float*)d_in[12];
  const float* root2   = (const float*)d_in[13];
  const float* msg_w   = (const float*)d_in[15];
  const float* msg_b   = (const float*)d_in[16];
  float* out = (float*)d_out;

  char* p = (char*)d_ws;
  size_t off = 0;
  auto alloc = [&](size_t bytes) -> char* {
    char* r = p + off;
    off += (bytes + 255) & ~(size_t)255;
    return r;
  };
  int*            cnt    = (int*)alloc(NSEG*4);
  int*            offs   = (int*)alloc(NSEG*4);
  int*            cursor = (int*)alloc(NSEG*4);
  unsigned int*   spk    = (unsigned int*)alloc(NEDGE*4);
  int*            total  = (int*)alloc(256);
  unsigned short* B1t    = (unsigned short*)alloc((size_t)256*640*2);
  unsigned short* BtV    = (unsigned short*)alloc((size_t)128*256*2);
  float*          me     = (float*)alloc(NGRAPH*EMB*4);
  float*          v      = (float*)alloc((size_t)NGRAPH*1280*4);
  unsigned short* xb     = (unsigned short*)alloc((size_t)MP*FEAT*2);
  unsigned short* s1     = (unsigned short*)alloc((size_t)MP*512*2);
  float*          D      = (float*)alloc((size_t)MP*128*4);
  float*          sc     = (float*)alloc(NNODE*4);

  k_zeroMe  <<<635, 256, 0, stream>>>(cnt, total, x, msg_w, msg_b, me);
  k_histPrep<<<18290, 256, 0, stream>>>(ei, et, cnt, node_x, xb, basis1, root1, B1t,
                                        basis2, root2, me, v);
  k_offsets <<<625, 256, 0, stream>>>(cnt, offs, cursor, total);
  k_scatter <<<1250, 256, 0, stream>>>(ei, et, cnt, cursor, spk);

  k_agg1  <<<1378, 256, 0, stream>>>(xb, offs, cnt, spk, comp1, s1, v, BtV);
  k_gemmHD<<<628, 256, 0, stream>>>(s1, xb, B1t, BtV, bias1, D);
  k_score2<<<5000, 256, 0, stream>>>(D, offs, cnt, spk, comp2, batch, sc);
  k_lsm   <<<NGRAPH, 256, 0, stream>>>(sc, out);
}

// Round 12
// 138.704 us; speedup vs baseline: 1.2662x; 1.0015x over previous
//
#include <hip/hip_runtime.h>
#include <hip/hip_bf16.h>

#define NEDGE 320000
#define NNODE 20000
#define MP    20096      // 157*128 padded rows
#define NRELS 8
#define NSEG  (NNODE*NRELS)   // 160000
#define FEAT  128
#define HID   256
#define EMB   128
#define NGRAPH 20
#define NPG   1000
#define NBASE 4

typedef __attribute__((ext_vector_type(4))) float f32x4;
typedef __attribute__((ext_vector_type(8))) __bf16 bf16x8;
typedef __attribute__((ext_vector_type(8))) unsigned short u16x8;

static __device__ __forceinline__ float bf2f(unsigned short u){
  union { unsigned int i; float f; } v; v.i = ((unsigned int)u) << 16; return v.f;
}
static __device__ __forceinline__ unsigned short f2bf(float f){
  union { float f; unsigned int i; } v; v.f = f;
  unsigned int x = v.i;
  return (unsigned short)((x + 0x7fffu + ((x >> 16) & 1u)) >> 16);
}

__device__ __forceinline__ void load_lds16(const void* g, void* l){
  __builtin_amdgcn_global_load_lds((const __attribute__((address_space(1))) void*)g,
                                   (__attribute__((address_space(3))) void*)l, 16, 0, 0);
}

// ---------------- fused init + me ----------------
__global__ void k_zeroMe(int* __restrict__ cnt, int* __restrict__ total,
                         const float* __restrict__ x, const float* __restrict__ mw,
                         const float* __restrict__ mb, float* __restrict__ me){
  int blk = blockIdx.x;
  if (blk < 625){
    int i = blk*256 + threadIdx.x;
    if (i < NSEG) cnt[i] = 0;
    if (i == 0) *total = 0;
  } else {
    int id = (blk-625)*256 + threadIdx.x;
    if (id >= NGRAPH*EMB) return;
    int g = id >> 7, e = id & 127;
    float s = mb[e];
    for (int i=0;i<HID;i++) s += x[g*HID + i] * mw[i*EMB + e];
    me[id] = s;
  }
}

// ---------------- fused hist + weight prep ----------------
// blocks 0..1249: hist ; 1250..11249: xb cvt ; 11250..11889: B1t ; 11890..18289: v
__global__ void k_histPrep(const int* __restrict__ ei, const int* __restrict__ et, int* __restrict__ cnt,
                           const float* __restrict__ xin, unsigned short* __restrict__ xb,
                           const float* __restrict__ basis, const float* __restrict__ root,
                           unsigned short* __restrict__ Bt,
                           const float* __restrict__ basis2, const float* __restrict__ root2,
                           const float* __restrict__ me, float* __restrict__ v){
  int blk = blockIdx.x;
  if (blk < 1250){
    int e = blk*256 + threadIdx.x;
    if (e < NEDGE){
      int key = ei[NEDGE + e]*NRELS + et[e];
      atomicAdd(&cnt[key], 1);
    }
  } else if (blk < 11250){
    int i = (blk-1250)*256 + threadIdx.x;
    if (i < NNODE*FEAT) xb[i] = f2bf(xin[i]);
  } else if (blk < 11890){
    int idx = (blk-11250)*256 + threadIdx.x;
    if (idx >= 256*640) return;
    int o = idx / 640, k = idx % 640;
    float val = (k < 512) ? basis[(size_t)k*256 + o] : root[(size_t)(k-512)*256 + o];
    Bt[(size_t)o*640 + k] = f2bf(val);
  } else {
    int w = threadIdx.x >> 6, lane = threadIdx.x & 63;
    int id = (blk-11890)*4 + w;
    if (id >= NGRAPH*1280) return;
    int g = id / 1280, k = id % 1280;
    const float* row = (k < 1024) ? (basis2 + (size_t)k*EMB) : (root2 + (size_t)(k-1024)*EMB);
    float2 a = *(const float2*)(row + lane*2);
    float2 m = *(const float2*)(me + g*EMB + lane*2);
    float p = a.x*m.x + a.y*m.y;
    #pragma unroll
    for (int d=32; d; d>>=1) p += __shfl_down(p, d);
    if (lane == 0) v[(size_t)g*1280 + k] = p;
  }
}

// Disjoint contiguous ranges per segment: wave prefix + one atomic per wave.
__global__ void k_offsets(const int* __restrict__ cnt, int* __restrict__ offs,
                          int* __restrict__ cursor, int* __restrict__ total){
  int i = blockIdx.x*256 + threadIdx.x;
  int lane = threadIdx.x & 63;
  int c = (i < NSEG) ? cnt[i] : 0;
  int inc = c;
  #pragma unroll
  for (int d=1; d<64; d<<=1){
    int vv = __shfl_up(inc, d);
    if (lane >= d) inc += vv;
  }
  __shared__ int wbase[4];
  if (lane == 63) wbase[threadIdx.x>>6] = atomicAdd(total, inc);
  __syncthreads();
  if (i < NSEG){
    int base = wbase[threadIdx.x>>6] + inc - c;
    offs[i] = base;
    cursor[i] = base;
  }
}

// scatter: single packed u32 per edge: src(15b) | r(3b) | cnt(14b)
__global__ void k_scatter(const int* __restrict__ ei, const int* __restrict__ et,
                          const int* __restrict__ cnt, int* __restrict__ cursor,
                          unsigned int* __restrict__ spk){
  int e = blockIdx.x*256 + threadIdx.x;
  if (e < NEDGE){
    int src = ei[e];
    int r = et[e];
    int key = ei[NEDGE + e]*NRELS + r;
    int pos = atomicAdd(&cursor[key], 1);
    int c = cnt[key]; if (c > 16383) c = 16383;
    spk[pos] = (unsigned int)src | ((unsigned int)r << 15) | ((unsigned int)c << 18);
  }
}

// ---------------- layer1 aggregation (16-lane groups, packed edges, unroll 8) + packV ----------------
__global__ void k_agg1(const unsigned short* __restrict__ xb, const int* __restrict__ offs,
                       const int* __restrict__ cnt, const unsigned int* __restrict__ spk,
                       const float* __restrict__ comp1, unsigned short* __restrict__ s1,
                       const float* __restrict__ v, unsigned short* __restrict__ BtV){
  if (blockIdx.x >= 1250){
    int idx = (blockIdx.x-1250)*256 + threadIdx.x;
    if (idx >= 128*256) return;
    int c = idx >> 8, k = idx & 255;
    float val = 0.f;
    if (c < 80)        val = v[(size_t)(c>>2)*1280 + (c&3)*256 + k];
    else if (c < 100)  val = v[(size_t)(c-80)*1280 + 1024 + k];
    BtV[idx] = f2bf(val);
    return;
  }
  __shared__ float c1s[32];
  if (threadIdx.x < 32) c1s[threadIdx.x] = comp1[threadIdx.x];
  __syncthreads();
  int grp = threadIdx.x >> 4, sl = threadIdx.x & 15;
  int n = blockIdx.x*16 + grp;
  int o0 = offs[n*NRELS];
  int C  = offs[n*NRELS+7] + cnt[n*NRELS+7] - o0;
  const unsigned int* pp = spk + o0;
  float u[NBASE][8] = {};
  int j = 0;
  for (; j+8 <= C; j += 8){
    unsigned int pk[8];
    u16x8 vv[8];
    #pragma unroll
    for (int t=0;t<8;t++) pk[t] = pp[j+t];
    #pragma unroll
    for (int t=0;t<8;t++) vv[t] = *(const u16x8*)(xb + (size_t)(pk[t] & 0x7FFF)*FEAT + sl*8);
    #pragma unroll
    for (int t=0;t<8;t++){
      float inv = __builtin_amdgcn_rcpf((float)(pk[t] >> 18));
      const float* cr = c1s + ((pk[t] >> 15) & 7)*4;
      #pragma unroll
      for (int b=0;b<NBASE;b++){
        float wb = cr[b]*inv;
        #pragma unroll
        for (int k=0;k<8;k++) u[b][k] += wb*bf2f(vv[t][k]);
      }
    }
  }
  for (; j+4 <= C; j += 4){
    unsigned int pk[4];
    u16x8 vv[4];
    #pragma unroll
    for (int t=0;t<4;t++) pk[t] = pp[j+t];
    #pragma unroll
    for (int t=0;t<4;t++) vv[t] = *(const u16x8*)(xb + (size_t)(pk[t] & 0x7FFF)*FEAT + sl*8);
    #pragma unroll
    for (int t=0;t<4;t++){
      float inv = __builtin_amdgcn_rcpf((float)(pk[t] >> 18));
      const float* cr = c1s + ((pk[t] >> 15) & 7)*4;
      #pragma unroll
      for (int b=0;b<NBASE;b++){
        float wb = cr[b]*inv;
        #pragma unroll
        for (int k=0;k<8;k++) u[b][k] += wb*bf2f(vv[t][k]);
      }
    }
  }
  for (; j < C; ++j){
    unsigned int pk = pp[j];
    u16x8 vv = *(const u16x8*)(xb + (size_t)(pk & 0x7FFF)*FEAT + sl*8);
    float inv = __builtin_amdgcn_rcpf((float)(pk >> 18));
    const float* cr = c1s + ((pk >> 15) & 7)*4;
    #pragma unroll
    for (int b=0;b<NBASE;b++){
      float wb = cr[b]*inv;
      #pragma unroll
      for (int k=0;k<8;k++) u[b][k] += wb*bf2f(vv[k]);
    }
  }
  #pragma unroll
  for (int b=0;b<NBASE;b++){
    u16x8 o8;
    #pragma unroll
    for (int k=0;k<8;k++) o8[k] = f2bf(u[b][k]);
    *(u16x8*)(s1 + (size_t)n*(NBASE*FEAT) + b*FEAT + sl*8) = o8;
  }
}

// ---------------- fused GEMM: h-tile (32x256, regs) -> relu -> LDS bf16 -> D-tile (32x128) ----------------
__global__ __launch_bounds__(256, 3)
void k_gemmHD(const unsigned short* __restrict__ A0,   // s1 [MP][512]
              const unsigned short* __restrict__ A1,   // xb [MP][128]
              const unsigned short* __restrict__ B1t,  // [256][640]
              const unsigned short* __restrict__ BtV,  // [128][256]
              const float* __restrict__ bias1,
              float* __restrict__ D)                   // [MP][128]
{
  __shared__ __align__(16) unsigned short As[32*64];     // 4 KB
  __shared__ __align__(16) unsigned short Bs[256*64];    // 32 KB (stage1; first 16KB reused stage2)
  __shared__ __align__(16) unsigned short hs[32*256];    // 16 KB

  const int tid = threadIdx.x;
  const int w = tid >> 6, lane = tid & 63;
  const int wr = w >> 1, wc = w & 1;
  const int m0 = blockIdx.x * 32;

  f32x4 acc[8];
  #pragma unroll
  for (int i=0;i<8;i++) acc[i] = (f32x4){0.f,0.f,0.f,0.f};

  // ---- stage 1 ----
  for (int kt=0; kt<10; ++kt){
    const int kb = kt*64;
    {
      const unsigned short* Ab; int ld, kk0;
      if (kb < 512){ Ab = A0; ld = 512; kk0 = kb; } else { Ab = A1; ld = 128; kk0 = kb-512; }
      int row = tid >> 3, slot = tid & 7;
      int srcs = slot ^ (row & 7);
      load_lds16(Ab + (size_t)(m0+row)*ld + kk0 + srcs*8, (char*)As + (w*64)*16);
    }
    #pragma unroll
    for (int t=0;t<8;t++){
      int c = t*256 + tid, row = c >> 3, slot = c & 7;
      int srcs = slot ^ (row & 7);
      load_lds16(B1t + (size_t)row*640 + kb + srcs*8, (char*)Bs + (t*256 + w*64)*16);
    }
    asm volatile("s_waitcnt vmcnt(0)" ::: "memory");
    __syncthreads();
    #pragma unroll
    for (int kk=0;kk<2;++kk){
      int arow = wr*16 + (lane & 15);
      int aslot = (kk*4 + (lane >> 4)) ^ (arow & 7);
      bf16x8 afr = *(const bf16x8*)(As + arow*64 + aslot*8);
      #pragma unroll
      for (int fn=0;fn<8;++fn){
        int brow = wc*128 + fn*16 + (lane & 15);
        int bslot = (kk*4 + (lane >> 4)) ^ (brow & 7);
        bf16x8 bfr = *(const bf16x8*)(Bs + brow*64 + bslot*8);
        acc[fn] = __builtin_amdgcn_mfma_f32_16x16x32_bf16(afr, bfr, acc[fn], 0, 0, 0);
      }
    }
    __syncthreads();
  }
  // h tile -> LDS (bias + relu, bf16, octet XOR swizzle on 8-slot groups)
  #pragma unroll
  for (int fn=0;fn<8;++fn){
    int col = wc*128 + fn*16 + (lane & 15);
    float b = bias1[col];
    int s = col >> 3;
    #pragma unroll
    for (int q=0;q<4;q++){
      int row = wr*16 + (lane >> 4)*4 + q;
      float val = acc[fn][q] + b;
      val = val > 0.f ? val : 0.f;
      int p = (s & ~7) | ((s & 7) ^ (row & 7));
      hs[row*256 + p*8 + (col & 7)] = f2bf(val);
    }
  }
  __syncthreads();

  // ---- stage 2 ----
  f32x4 acc2[4];
  #pragma unroll
  for (int i=0;i<4;i++) acc2[i] = (f32x4){0.f,0.f,0.f,0.f};
  for (int kt=0; kt<4; ++kt){
    const int kb = kt*64;
    #pragma unroll
    for (int t=0;t<4;t++){
      int c = t*256 + tid, row = c >> 3, slot = c & 7;
      int srcs = slot ^ (row & 7);
      load_lds16(BtV + (size_t)row*256 + kb + srcs*8, (char*)Bs + (t*256 + w*64)*16);
    }
    asm volatile("s_waitcnt vmcnt(0)" ::: "memory");
    __syncthreads();
    #pragma unroll
    for (int kk=0;kk<2;++kk){
      int arow = wr*16 + (lane & 15);
      int slog = kt*8 + kk*4 + (lane >> 4);
      int ap = (slog & ~7) | ((slog & 7) ^ (arow & 7));
      bf16x8 afr = *(const bf16x8*)(hs + arow*256 + ap*8);
      #pragma unroll
      for (int fn=0;fn<4;++fn){
        int brow = wc*64 + fn*16 + (lane & 15);
        int bslot = (kk*4 + (lane >> 4)) ^ (brow & 7);
        bf16x8 bfr = *(const bf16x8*)(Bs + brow*64 + bslot*8);
        acc2[fn] = __builtin_amdgcn_mfma_f32_16x16x32_bf16(afr, bfr, acc2[fn], 0, 0, 0);
      }
    }
    __syncthreads();
  }
  #pragma unroll
  for (int fn=0;fn<4;++fn){
    int col = wc*64 + fn*16 + (lane & 15);
    #pragma unroll
    for (int q=0;q<4;q++){
      int row = m0 + wr*16 + (lane >> 4)*4 + q;
      D[(size_t)row*128 + col] = acc2[fn][q];
    }
  }
}

// score[n] = sum_e inv_e * dot4(comp2[r_e], D[src_e][4g..]) + D[n][80+g]
// 16-lane groups: 4 nodes per wave, lane-per-edge -> all 64 lanes gathering
__global__ void k_score2(const float* __restrict__ D, const int* __restrict__ offs,
                         const int* __restrict__ cnt, const unsigned int* __restrict__ spk,
                         const float* __restrict__ comp2, const int* __restrict__ batch,
                         float* __restrict__ sc){
  __shared__ float4 c2s[8];
  if (threadIdx.x < 8) c2s[threadIdx.x] = ((const float4*)comp2)[threadIdx.x];
  __syncthreads();
  int grp = threadIdx.x >> 4, sl = threadIdx.x & 15;
  int n = blockIdx.x*16 + grp;
  if (n >= NNODE) return;
  int g = batch[n];
  int o0 = offs[n*NRELS];
  int C  = offs[n*NRELS+7] + cnt[n*NRELS+7] - o0;
  float acc = 0.f;
  for (int j = sl; j < C; j += 16){
    unsigned int pk = spk[o0 + j];
    int s = pk & 0x7FFF;
    float inv = __builtin_amdgcn_rcpf((float)(pk >> 18));
    float4 dv = *(const float4*)(D + (size_t)s*128 + g*4);
    float4 cw = c2s[(pk >> 15) & 7];
    acc += inv*(cw.x*dv.x + cw.y*dv.y + cw.z*dv.z + cw.w*dv.w);
  }
  #pragma unroll
  for (int d=8; d; d>>=1) acc += __shfl_down(acc, d, 16);
  if (sl == 0) sc[n] = acc + D[(size_t)n*128 + 80 + g];
}

__global__ void k_lsm(const float* __restrict__ sc, float* __restrict__ out){
  __shared__ float sb[1024];
  __shared__ float red[256];
  int g = blockIdx.x, t = threadIdx.x;
  float lm = -1e30f;
  for (int j=t; j<1024; j+=256){
    float v = (j < NPG) ? sc[g*NPG + j] : -1e30f;
    sb[j] = v; lm = fmaxf(lm, v);
  }
  red[t] = lm; __syncthreads();
  for (int off=128; off; off>>=1){ if (t < off) red[t] = fmaxf(red[t], red[t+off]); __syncthreads(); }
  float mx = red[0]; __syncthreads();
  float ls = 0.f;
  for (int j=t; j<1024; j+=256){ if (j < NPG) ls += expf(sb[j] - mx); }
  red[t] = ls; __syncthreads();
  for (int off=128; off; off>>=1){ if (t < off) red[t] += red[t+off]; __syncthreads(); }
  float lse = mx + logf(red[0]);
  for (int j=t; j<NPG; j+=256) out[g*NPG + j] = sb[j] - lse;
}

// ---------------- launch ----------------
extern "C" void kernel_launch(void* const* d_in, const int* in_sizes, int n_in,
                              void* d_out, int out_size, void* d_ws, size_t ws_size,
                              hipStream_t stream) {
  const float* x       = (const float*)d_in[0];
  const float* node_x  = (const float*)d_in[2];
  const int*   ei      = (const int*)d_in[3];
  const int*   et      = (const int*)d_in[4];
  const int*   batch   = (const int*)d_in[5];
  const float* comp1   = (const float*)d_in[7];
  const float* basis1  = (const float*)d_in[8];
  const float* root1   = (const float*)d_in[9];
  const float* bias1   = (const float*)d_in[10];
  const float* comp2   = (const float*)d_in[11];
  const float* basis2  = (const float*)d_in[12];
  const float* root2   = (const float*)d_in[13];
  const float* msg_w   = (const float*)d_in[15];
  const float* msg_b   = (const float*)d_in[16];
  float* out = (float*)d_out;

  char* p = (char*)d_ws;
  size_t off = 0;
  auto alloc = [&](size_t bytes) -> char* {
    char* r = p + off;
    off += (bytes + 255) & ~(size_t)255;
    return r;
  };
  int*            cnt    = (int*)alloc(NSEG*4);
  int*            offs   = (int*)alloc(NSEG*4);
  int*            cursor = (int*)alloc(NSEG*4);
  unsigned int*   spk    = (unsigned int*)alloc(NEDGE*4);
  int*            total  = (int*)alloc(256);
  unsigned short* B1t    = (unsigned short*)alloc((size_t)256*640*2);
  unsigned short* BtV    = (unsigned short*)alloc((size_t)128*256*2);
  float*          me     = (float*)alloc(NGRAPH*EMB*4);
  float*          v      = (float*)alloc((size_t)NGRAPH*1280*4);
  unsigned short* xb     = (unsigned short*)alloc((size_t)MP*FEAT*2);
  unsigned short* s1     = (unsigned short*)alloc((size_t)MP*512*2);
  float*          D      = (float*)alloc((size_t)MP*128*4);
  float*          sc     = (float*)alloc(NNODE*4);

  k_zeroMe  <<<635, 256, 0, stream>>>(cnt, total, x, msg_w, msg_b, me);
  k_histPrep<<<18290, 256, 0, stream>>>(ei, et, cnt, node_x, xb, basis1, root1, B1t,
                                        basis2, root2, me, v);
  k_offsets <<<625, 256, 0, stream>>>(cnt, offs, cursor, total);
  k_scatter <<<1250, 256, 0, stream>>>(ei, et, cnt, cursor, spk);

  k_agg1  <<<1378, 256, 0, stream>>>(xb, offs, cnt, spk, comp1, s1, v, BtV);
  k_gemmHD<<<628, 256, 0, stream>>>(s1, xb, B1t, BtV, bias1, D);
  k_score2<<<1250, 256, 0, stream>>>(D, offs, cnt, spk, comp2, batch, sc);
  k_lsm   <<<NGRAPH, 256, 0, stream>>>(sc, out);
}